// Round 1
// baseline (302.970 us; speedup 1.0000x reference)
//
#include <hip/hip_runtime.h>
#include <math.h>

#define BATCH 256
#define CLS 500
#define ATT_DIM_ 1024
#define IMG_DIM_ 1024
#define ATT_HC_ 256
#define HIDDEN_ 1024
#define T_TEMP_ 10.0f
#define THRESH_ 0.86602540378443864676f
#define NEGV -9.0e15f

// ---------------- generic f32 tiled GEMM: C[M,N] = A[M,K] @ B[K,N] (+bias) ----------------
// BM=BN=64, BK=16, 256 threads, 4x4 micro-tile per thread.
__global__ __launch_bounds__(256) void gemm_f32(
    const float* __restrict__ A, const float* __restrict__ B,
    const float* __restrict__ bias, float* __restrict__ C,
    int M, int N, int K)
{
    __shared__ float As[64][20];   // padded: row stride 80B (multiple of 16B, breaks bank alias)
    __shared__ float Bs[16][64];
    const int t  = threadIdx.x;
    const int tb = t >> 4, tc = t & 15;
    const int m0 = blockIdx.x * 64, n0 = blockIdx.y * 64;

    const int arow  = t >> 2;          // 0..63
    const int acol4 = (t & 3) * 4;     // 0,4,8,12
    const int brow  = t >> 4;          // 0..15
    const int bcol4 = (t & 15) * 4;    // 0..60

    float acc[4][4] = {};

    for (int kb = 0; kb < K; kb += 16) {
        float4 av = make_float4(0.f, 0.f, 0.f, 0.f);
        if (m0 + arow < M)
            av = *(const float4*)&A[(size_t)(m0 + arow) * K + kb + acol4];
        *(float4*)&As[arow][acol4] = av;

        float4 bv = *(const float4*)&B[(size_t)(kb + brow) * N + n0 + bcol4];
        *(float4*)&Bs[brow][bcol4] = bv;
        __syncthreads();

        #pragma unroll
        for (int k4 = 0; k4 < 4; ++k4) {
            float4 a0 = *(float4*)&As[tb +  0][k4 * 4];
            float4 a1 = *(float4*)&As[tb + 16][k4 * 4];
            float4 a2 = *(float4*)&As[tb + 32][k4 * 4];
            float4 a3 = *(float4*)&As[tb + 48][k4 * 4];
            #pragma unroll
            for (int e = 0; e < 4; ++e) {
                const int k = k4 * 4 + e;
                float b0 = Bs[k][tc +  0];
                float b1 = Bs[k][tc + 16];
                float b2 = Bs[k][tc + 32];
                float b3 = Bs[k][tc + 48];
                float a_[4] = { (&a0.x)[e], (&a1.x)[e], (&a2.x)[e], (&a3.x)[e] };
                #pragma unroll
                for (int i = 0; i < 4; ++i) {
                    acc[i][0] += a_[i] * b0;
                    acc[i][1] += a_[i] * b1;
                    acc[i][2] += a_[i] * b2;
                    acc[i][3] += a_[i] * b3;
                }
            }
        }
        __syncthreads();
    }

    #pragma unroll
    for (int i = 0; i < 4; ++i) {
        const int m = m0 + tb + 16 * i;
        if (m >= M) continue;
        #pragma unroll
        for (int j = 0; j < 4; ++j) {
            const int n = n0 + tc + 16 * j;
            float v = acc[i][j];
            if (bias) v += bias[n];
            C[(size_t)m * N + n] = v;
        }
    }
}

// ---------------- row-normalize g[500,256] in place ----------------
__global__ __launch_bounds__(256) void row_normalize(float* __restrict__ g)
{
    const int c = blockIdx.x, t = threadIdx.x;
    float v  = g[(size_t)c * 256 + t];
    float ss = v * v;
    #pragma unroll
    for (int off = 32; off >= 1; off >>= 1) ss += __shfl_down(ss, off);
    __shared__ float red[4];
    const int wave = t >> 6, lane = t & 63;
    if (lane == 0) red[wave] = ss;
    __syncthreads();
    const float tot = red[0] + red[1] + red[2] + red[3];
    const float rn  = 1.f / sqrtf(tot);
    g[(size_t)c * 256 + t] = v * rn;
}

// ---------------- per-class-row: sim row -> masked softmax -> att_outs row ----------------
__global__ __launch_bounds__(256) void attention_kernel(
    const float* __restrict__ gn, const float* __restrict__ attrs,
    float* __restrict__ att_outs)
{
    const int c = blockIdx.x, t = threadIdx.x;
    __shared__ float gnc[256];
    __shared__ float p_s[512];
    __shared__ float redm[4];
    __shared__ float reds[4];

    gnc[t] = gn[(size_t)c * 256 + t];
    p_s[t] = NEGV; p_s[t + 256] = NEGV;
    __syncthreads();

    float vmax = NEGV;
    for (int c2 = t; c2 < CLS; c2 += 256) {
        const float* gr = &gn[(size_t)c2 * 256];
        float d = 0.f;
        for (int k = 0; k < 256; ++k) d += gnc[k] * gr[k];
        p_s[c2] = d;
        vmax = fmaxf(vmax, (d > THRESH_) ? d : NEGV);
    }
    #pragma unroll
    for (int off = 32; off >= 1; off >>= 1) vmax = fmaxf(vmax, __shfl_down(vmax, off));
    const int wave = t >> 6, lane = t & 63;
    if (lane == 0) redm[wave] = vmax;
    __syncthreads();
    const float m = fmaxf(fmaxf(redm[0], redm[1]), fmaxf(redm[2], redm[3]));

    float vsum = 0.f;
    for (int c2 = t; c2 < CLS; c2 += 256) {
        float d  = p_s[c2];
        float pv = (d > THRESH_) ? expf(T_TEMP_ * (d - m)) : 0.f;
        p_s[c2] = pv;
        vsum += pv;
    }
    #pragma unroll
    for (int off = 32; off >= 1; off >>= 1) vsum += __shfl_down(vsum, off);
    if (lane == 0) reds[wave] = vsum;
    __syncthreads();  // also orders p_s writes before the scan below
    const float inv = 1.f / (reds[0] + reds[1] + reds[2] + reds[3]);

    // attention row is exactly sparse (masked -> 0); skip zeros (wave-uniform branch)
    float acc[4] = {0.f, 0.f, 0.f, 0.f};
    for (int c2 = 0; c2 < CLS; ++c2) {
        const float pv = p_s[c2];
        if (pv > 0.f) {
            const float* ar = &attrs[(size_t)c2 * 1024 + t];
            #pragma unroll
            for (int j = 0; j < 4; ++j) acc[j] += pv * ar[256 * j];
        }
    }
    #pragma unroll
    for (int j = 0; j < 4; ++j)
        att_outs[(size_t)c * 1024 + t + 256 * j] = acc[j] * inv;
}

// ---------------- fused relu-reduction partials ----------------
// partial[nh][b][c] = sum_{h in chunk nh} relu(img_h[b,h]+sem_h[c,h]) * fc_w[h]
// grid (4, 8, 8): 64x64 output tile per block, 128 h per chunk, 256 threads, 4x4/thread.
__global__ __launch_bounds__(256) void fused_out_partial(
    const float* __restrict__ img_h, const float* __restrict__ sem_h,
    const float* __restrict__ fc_w, float* __restrict__ partial)
{
    __shared__ float imgs[64][68];   // +4 pad: row bank-offset stride 4, breaks 64-float alias
    __shared__ float sems[64][68];
    __shared__ float fcs[128];

    const int t  = threadIdx.x;
    const int tb = t >> 4, tc = t & 15;
    const int b0 = blockIdx.x * 64, c0 = blockIdx.y * 64;
    const int h0 = blockIdx.z * 128;

    if (t < 32) *(float4*)&fcs[t * 4] = *(const float4*)&fc_w[h0 + t * 4];

    float acc[4][4] = {};

    for (int hs = 0; hs < 2; ++hs) {
        const int hb = h0 + hs * 64;
        #pragma unroll
        for (int i = 0; i < 4; ++i) {
            const int row = (t >> 4) + 16 * i;
            const int col = (t & 15) * 4;
            *(float4*)&imgs[row][col] =
                *(const float4*)&img_h[(size_t)(b0 + row) * 1024 + hb + col];
            float4 sv = make_float4(0.f, 0.f, 0.f, 0.f);
            if (c0 + row < CLS)
                sv = *(const float4*)&sem_h[(size_t)(c0 + row) * 1024 + hb + col];
            *(float4*)&sems[row][col] = sv;
        }
        __syncthreads();

        #pragma unroll
        for (int h4 = 0; h4 < 16; ++h4) {
            float4 ia[4], sa[4];
            #pragma unroll
            for (int i = 0; i < 4; ++i) ia[i] = *(float4*)&imgs[tb + 16 * i][h4 * 4];
            #pragma unroll
            for (int j = 0; j < 4; ++j) sa[j] = *(float4*)&sems[tc + 16 * j][h4 * 4];
            #pragma unroll
            for (int e = 0; e < 4; ++e) {
                const float w = fcs[hs * 64 + h4 * 4 + e];
                #pragma unroll
                for (int i = 0; i < 4; ++i) {
                    const float iv = (&ia[i].x)[e];
                    #pragma unroll
                    for (int j = 0; j < 4; ++j) {
                        const float sv = (&sa[j].x)[e];
                        acc[i][j] += fmaxf(iv + sv, 0.f) * w;
                    }
                }
            }
        }
        __syncthreads();
    }

    const int nh = blockIdx.z;
    #pragma unroll
    for (int i = 0; i < 4; ++i) {
        const int b = b0 + tb + 16 * i;
        #pragma unroll
        for (int j = 0; j < 4; ++j) {
            const int cc = c0 + tc + 16 * j;
            if (cc < CLS)
                partial[((size_t)nh * BATCH + b) * CLS + cc] = acc[i][j];
        }
    }
}

// ---------------- finalize: out[b,c] = fc_b + sum_nh partial ----------------
__global__ __launch_bounds__(256) void finalize_kernel(
    const float* __restrict__ partial, const float* __restrict__ fc_b,
    float* __restrict__ out)
{
    const int idx = blockIdx.x * 256 + threadIdx.x;
    if (idx >= BATCH * CLS) return;
    const int b = idx / CLS, cc = idx % CLS;
    float s = fc_b[0];
    #pragma unroll
    for (int nh = 0; nh < 8; ++nh)
        s += partial[((size_t)nh * BATCH + b) * CLS + cc];
    out[idx] = s;
}

extern "C" void kernel_launch(void* const* d_in, const int* in_sizes, int n_in,
                              void* d_out, int out_size, void* d_ws, size_t ws_size,
                              hipStream_t stream)
{
    const float* image_feats = (const float*)d_in[0];
    const float* attributes  = (const float*)d_in[1];
    const float* att_g       = (const float*)d_in[3];
    const float* img_w       = (const float*)d_in[4];
    const float* sem_w       = (const float*)d_in[5];
    const float* sem_b       = (const float*)d_in[6];
    const float* fc_w        = (const float*)d_in[7];
    const float* fc_b        = (const float*)d_in[8];
    float* out = (float*)d_out;

    char* ws = (char*)d_ws;
    float* gn       = (float*)(ws);              // 500*256  = 512000 B
    float* att_outs = (float*)(ws + 0x080000);   // 500*1024 = 2048000 B
    float* img_h    = (float*)(ws + 0x280000);   // 256*1024 = 1048576 B
    float* sem_h    = (float*)(ws + 0x380000);   // 500*1024 = 2048000 B
    float* partial  = (float*)(ws + 0x580000);   // 8*256*500*4 = 4096000 B  (total ~9.5 MB)

    // 1. g = attributes @ att_g   [500,256]
    gemm_f32<<<dim3((CLS + 63) / 64, ATT_HC_ / 64), 256, 0, stream>>>(
        attributes, att_g, nullptr, gn, CLS, ATT_HC_, ATT_DIM_);
    // 2. row-normalize -> gn
    row_normalize<<<CLS, 256, 0, stream>>>(gn);
    // 3. masked softmax attention -> att_outs  [500,1024]
    attention_kernel<<<CLS, 256, 0, stream>>>(gn, attributes, att_outs);
    // 4. img_h = image_feats @ img_w   [256,1024]
    gemm_f32<<<dim3(BATCH / 64, HIDDEN_ / 64), 256, 0, stream>>>(
        image_feats, img_w, nullptr, img_h, BATCH, HIDDEN_, IMG_DIM_);
    // 5. sem_h = att_outs @ sem_w + sem_b   [500,1024]
    gemm_f32<<<dim3((CLS + 63) / 64, HIDDEN_ / 64), 256, 0, stream>>>(
        att_outs, sem_w, sem_b, sem_h, CLS, HIDDEN_, ATT_DIM_);
    // 6. fused relu-reduction partials over 8 h-chunks
    fused_out_partial<<<dim3(BATCH / 64, (CLS + 63) / 64, 8), 256, 0, stream>>>(
        img_h, sem_h, fc_w, partial);
    // 7. finalize
    finalize_kernel<<<(BATCH * CLS + 255) / 256, 256, 0, stream>>>(partial, fc_b, out);
}

// Round 2
// 143.092 us; speedup vs baseline: 2.1173x; 2.1173x over previous
//
#include <hip/hip_runtime.h>
#include <math.h>

#define BATCH 256
#define CLS 500
#define ATT_DIM_ 1024
#define IMG_DIM_ 1024
#define ATT_HC_ 256
#define HIDDEN_ 1024
#define T_TEMP_ 10.0f
#define THRESH_ 0.86602540378443864676f
#define NEGV -9.0e15f

// ---------------- generic f32 tiled GEMM with grid split-K ----------------
// C/partial[M,N]; BM=BN=64, BK=16, 256 threads, 4x4 micro-tile per thread.
// blockIdx.z = K-split index; klen = K elements per split.
// If gridDim.z>1, writes partial at C + z*M*N (bias must be nullptr; reduce adds it).
__global__ __launch_bounds__(256) void gemm_f32(
    const float* __restrict__ A, const float* __restrict__ B,
    const float* __restrict__ bias, float* __restrict__ C,
    int M, int N, int K, int klen)
{
    __shared__ float As[64][20];   // padded: breaks bank alias
    __shared__ float Bs[16][64];
    const int t  = threadIdx.x;
    const int tb = t >> 4, tc = t & 15;
    const int m0 = blockIdx.x * 64, n0 = blockIdx.y * 64;
    const int k0 = blockIdx.z * klen;

    const int arow  = t >> 2;          // 0..63
    const int acol4 = (t & 3) * 4;     // 0,4,8,12
    const int brow  = t >> 4;          // 0..15
    const int bcol4 = (t & 15) * 4;    // 0..60

    float* Cw = C + (gridDim.z > 1 ? (size_t)blockIdx.z * M * N : 0);

    float acc[4][4] = {};

    for (int kb = k0; kb < k0 + klen; kb += 16) {
        float4 av = make_float4(0.f, 0.f, 0.f, 0.f);
        if (m0 + arow < M)
            av = *(const float4*)&A[(size_t)(m0 + arow) * K + kb + acol4];
        *(float4*)&As[arow][acol4] = av;

        float4 bv = *(const float4*)&B[(size_t)(kb + brow) * N + n0 + bcol4];
        *(float4*)&Bs[brow][bcol4] = bv;
        __syncthreads();

        #pragma unroll
        for (int k4 = 0; k4 < 4; ++k4) {
            float4 a0 = *(float4*)&As[tb +  0][k4 * 4];
            float4 a1 = *(float4*)&As[tb + 16][k4 * 4];
            float4 a2 = *(float4*)&As[tb + 32][k4 * 4];
            float4 a3 = *(float4*)&As[tb + 48][k4 * 4];
            #pragma unroll
            for (int e = 0; e < 4; ++e) {
                const int k = k4 * 4 + e;
                float b0 = Bs[k][tc +  0];
                float b1 = Bs[k][tc + 16];
                float b2 = Bs[k][tc + 32];
                float b3 = Bs[k][tc + 48];
                float a_[4] = { (&a0.x)[e], (&a1.x)[e], (&a2.x)[e], (&a3.x)[e] };
                #pragma unroll
                for (int i = 0; i < 4; ++i) {
                    acc[i][0] += a_[i] * b0;
                    acc[i][1] += a_[i] * b1;
                    acc[i][2] += a_[i] * b2;
                    acc[i][3] += a_[i] * b3;
                }
            }
        }
        __syncthreads();
    }

    #pragma unroll
    for (int i = 0; i < 4; ++i) {
        const int m = m0 + tb + 16 * i;
        if (m >= M) continue;
        #pragma unroll
        for (int j = 0; j < 4; ++j) {
            const int n = n0 + tc + 16 * j;
            float v = acc[i][j];
            if (bias) v += bias[n];
            Cw[(size_t)m * N + n] = v;
        }
    }
}

// ---------------- reduce split-K partials (+bias) ----------------
__global__ __launch_bounds__(256) void reduce_splitk(
    const float* __restrict__ part, const float* __restrict__ bias,
    float* __restrict__ C, int MN, int N, int ks)
{
    const int idx = blockIdx.x * 256 + threadIdx.x;
    if (idx >= MN) return;
    float s = bias ? bias[idx % N] : 0.f;
    for (int i = 0; i < ks; ++i) s += part[(size_t)i * MN + idx];
    C[idx] = s;
}

// ---------------- row-normalize g[500,256] in place ----------------
__global__ __launch_bounds__(256) void row_normalize(float* __restrict__ g)
{
    const int c = blockIdx.x, t = threadIdx.x;
    float v  = g[(size_t)c * 256 + t];
    float ss = v * v;
    #pragma unroll
    for (int off = 32; off >= 1; off >>= 1) ss += __shfl_down(ss, off);
    __shared__ float red[4];
    const int wave = t >> 6, lane = t & 63;
    if (lane == 0) red[wave] = ss;
    __syncthreads();
    const float tot = red[0] + red[1] + red[2] + red[3];
    const float rn  = 1.f / sqrtf(tot);
    g[(size_t)c * 256 + t] = v * rn;
}

// ---------------- per-class-row: sim row -> masked softmax -> att_outs row ----------------
__global__ __launch_bounds__(256) void attention_kernel(
    const float* __restrict__ gn, const float* __restrict__ attrs,
    float* __restrict__ att_outs)
{
    const int c = blockIdx.x, t = threadIdx.x;
    __shared__ float gnc[256];
    __shared__ float p_s[512];
    __shared__ float redm[4];
    __shared__ float reds[4];

    gnc[t] = gn[(size_t)c * 256 + t];
    p_s[t] = NEGV; p_s[t + 256] = NEGV;
    __syncthreads();

    float vmax = NEGV;
    for (int c2 = t; c2 < CLS; c2 += 256) {
        const float* gr = &gn[(size_t)c2 * 256];
        float d = 0.f;
        for (int k = 0; k < 256; ++k) d += gnc[k] * gr[k];
        p_s[c2] = d;
        vmax = fmaxf(vmax, (d > THRESH_) ? d : NEGV);
    }
    #pragma unroll
    for (int off = 32; off >= 1; off >>= 1) vmax = fmaxf(vmax, __shfl_down(vmax, off));
    const int wave = t >> 6, lane = t & 63;
    if (lane == 0) redm[wave] = vmax;
    __syncthreads();
    const float m = fmaxf(fmaxf(redm[0], redm[1]), fmaxf(redm[2], redm[3]));

    float vsum = 0.f;
    for (int c2 = t; c2 < CLS; c2 += 256) {
        float d  = p_s[c2];
        float pv = (d > THRESH_) ? expf(T_TEMP_ * (d - m)) : 0.f;
        p_s[c2] = pv;
        vsum += pv;
    }
    #pragma unroll
    for (int off = 32; off >= 1; off >>= 1) vsum += __shfl_down(vsum, off);
    if (lane == 0) reds[wave] = vsum;
    __syncthreads();  // also orders p_s writes before the scan below
    const float inv = 1.f / (reds[0] + reds[1] + reds[2] + reds[3]);

    // attention row is exactly sparse (masked -> 0); skip zeros (wave-uniform branch)
    float acc[4] = {0.f, 0.f, 0.f, 0.f};
    for (int c2 = 0; c2 < CLS; ++c2) {
        const float pv = p_s[c2];
        if (pv > 0.f) {
            const float* ar = &attrs[(size_t)c2 * 1024 + t];
            #pragma unroll
            for (int j = 0; j < 4; ++j) acc[j] += pv * ar[256 * j];
        }
    }
    #pragma unroll
    for (int j = 0; j < 4; ++j)
        att_outs[(size_t)c * 1024 + t + 256 * j] = acc[j] * inv;
}

// ---------------- fused relu-reduction partials ----------------
// partial[nh][b][c] = sum_{h in chunk nh} relu(img_h[b,h]+sem_h[c,h]) * fc_w[h]
// 64x64 output tile per block, h_per h per chunk (64 or 128), 256 threads, 4x4/thread.
__global__ __launch_bounds__(256) void fused_out_partial(
    const float* __restrict__ img_h, const float* __restrict__ sem_h,
    const float* __restrict__ fc_w, float* __restrict__ partial, int h_per)
{
    __shared__ float imgs[64][68];   // +4 pad breaks 64-float bank alias
    __shared__ float sems[64][68];
    __shared__ float fcs[128];

    const int t  = threadIdx.x;
    const int tb = t >> 4, tc = t & 15;
    const int b0 = blockIdx.x * 64, c0 = blockIdx.y * 64;
    const int h0 = blockIdx.z * h_per;

    if (t < (h_per >> 2)) *(float4*)&fcs[t * 4] = *(const float4*)&fc_w[h0 + t * 4];

    float acc[4][4] = {};

    for (int hs = 0; hs < (h_per >> 6); ++hs) {
        const int hb = h0 + hs * 64;
        #pragma unroll
        for (int i = 0; i < 4; ++i) {
            const int row = (t >> 4) + 16 * i;
            const int col = (t & 15) * 4;
            *(float4*)&imgs[row][col] =
                *(const float4*)&img_h[(size_t)(b0 + row) * 1024 + hb + col];
            float4 sv = make_float4(0.f, 0.f, 0.f, 0.f);
            if (c0 + row < CLS)
                sv = *(const float4*)&sem_h[(size_t)(c0 + row) * 1024 + hb + col];
            *(float4*)&sems[row][col] = sv;
        }
        __syncthreads();

        #pragma unroll
        for (int h4 = 0; h4 < 16; ++h4) {
            float4 ia[4], sa[4];
            #pragma unroll
            for (int i = 0; i < 4; ++i) ia[i] = *(float4*)&imgs[tb + 16 * i][h4 * 4];
            #pragma unroll
            for (int j = 0; j < 4; ++j) sa[j] = *(float4*)&sems[tc + 16 * j][h4 * 4];
            #pragma unroll
            for (int e = 0; e < 4; ++e) {
                const float w = fcs[hs * 64 + h4 * 4 + e];
                #pragma unroll
                for (int i = 0; i < 4; ++i) {
                    const float iv = (&ia[i].x)[e];
                    #pragma unroll
                    for (int j = 0; j < 4; ++j) {
                        const float sv = (&sa[j].x)[e];
                        acc[i][j] += fmaxf(iv + sv, 0.f) * w;
                    }
                }
            }
        }
        __syncthreads();
    }

    const int nh = blockIdx.z;
    #pragma unroll
    for (int i = 0; i < 4; ++i) {
        const int b = b0 + tb + 16 * i;
        #pragma unroll
        for (int j = 0; j < 4; ++j) {
            const int cc = c0 + tc + 16 * j;
            if (cc < CLS)
                partial[((size_t)nh * BATCH + b) * CLS + cc] = acc[i][j];
        }
    }
}

// ---------------- finalize: out[b,c] = fc_b + sum_nh partial ----------------
__global__ __launch_bounds__(256) void finalize_kernel(
    const float* __restrict__ partial, const float* __restrict__ fc_b,
    float* __restrict__ out, int nsplit)
{
    const int idx = blockIdx.x * 256 + threadIdx.x;
    if (idx >= BATCH * CLS) return;
    float s = fc_b[0];
    for (int nh = 0; nh < nsplit; ++nh)
        s += partial[(size_t)nh * BATCH * CLS + idx];
    out[idx] = s;
}

extern "C" void kernel_launch(void* const* d_in, const int* in_sizes, int n_in,
                              void* d_out, int out_size, void* d_ws, size_t ws_size,
                              hipStream_t stream)
{
    const float* image_feats = (const float*)d_in[0];
    const float* attributes  = (const float*)d_in[1];
    const float* att_g       = (const float*)d_in[3];
    const float* img_w       = (const float*)d_in[4];
    const float* sem_w       = (const float*)d_in[5];
    const float* sem_b       = (const float*)d_in[6];
    const float* fc_w        = (const float*)d_in[7];
    const float* fc_b        = (const float*)d_in[8];
    float* out = (float*)d_out;

    char* ws = (char*)d_ws;
    float* gn       = (float*)(ws);              // 500*256*4  = 512000 B
    float* att_outs = (float*)(ws + 0x080000);   // 500*1024*4 = 2048000 B
    float* img_h    = (float*)(ws + 0x280000);   // 256*1024*4 = 1048576 B
    float* sem_h    = (float*)(ws + 0x380000);   // 500*1024*4 = 2048000 B
    float* scratch  = (float*)(ws + 0x580000);   // shared: split-K partials / out partials

    // guaranteed: ws_size >= 0x580000 + 4,096,000 (round-1 footprint passed)
    const size_t avail = ws_size - 0x580000;
    auto pick_ks = [&](size_t mn) {
        int ks = 8;
        while (ks > 1 && (size_t)ks * mn * 4 > avail) ks >>= 1;
        return ks;
    };

    // 1. g = attributes @ att_g   [500,256], K=1024
    {
        const int M = CLS, N = ATT_HC_, K = ATT_DIM_;
        const int ks = pick_ks((size_t)M * N);
        gemm_f32<<<dim3((M + 63) / 64, N / 64, ks), 256, 0, stream>>>(
            attributes, att_g, nullptr, ks == 1 ? gn : scratch, M, N, K, K / ks);
        if (ks > 1)
            reduce_splitk<<<(M * N + 255) / 256, 256, 0, stream>>>(
                scratch, nullptr, gn, M * N, N, ks);
    }
    // 2. row-normalize -> gn
    row_normalize<<<CLS, 256, 0, stream>>>(gn);
    // 3. masked softmax attention -> att_outs  [500,1024]
    attention_kernel<<<CLS, 256, 0, stream>>>(gn, attributes, att_outs);
    // 4. img_h = image_feats @ img_w   [256,1024], K=1024
    {
        const int M = BATCH, N = HIDDEN_, K = IMG_DIM_;
        const int ks = pick_ks((size_t)M * N);
        gemm_f32<<<dim3(M / 64, N / 64, ks), 256, 0, stream>>>(
            image_feats, img_w, nullptr, ks == 1 ? img_h : scratch, M, N, K, K / ks);
        if (ks > 1)
            reduce_splitk<<<(M * N + 255) / 256, 256, 0, stream>>>(
                scratch, nullptr, img_h, M * N, N, ks);
    }
    // 5. sem_h = att_outs @ sem_w + sem_b   [500,1024], K=1024
    {
        const int M = CLS, N = HIDDEN_, K = ATT_DIM_;
        const int ks = pick_ks((size_t)M * N);
        gemm_f32<<<dim3((M + 63) / 64, N / 64, ks), 256, 0, stream>>>(
            att_outs, sem_w, ks == 1 ? sem_b : nullptr, ks == 1 ? sem_h : scratch,
            M, N, K, K / ks);
        if (ks > 1)
            reduce_splitk<<<(M * N + 255) / 256, 256, 0, stream>>>(
                scratch, sem_b, sem_h, M * N, N, ks);
    }
    // 6. fused relu-reduction partials over h-chunks (reuses scratch region)
    {
        const int nh = (avail >= (size_t)16 * BATCH * CLS * 4) ? 16 : 8;
        const int h_per = HIDDEN_ / nh;
        fused_out_partial<<<dim3(BATCH / 64, (CLS + 63) / 64, nh), 256, 0, stream>>>(
            img_h, sem_h, fc_w, scratch, h_per);
        // 7. finalize
        finalize_kernel<<<(BATCH * CLS + 255) / 256, 256, 0, stream>>>(
            scratch, fc_b, out, nh);
    }
}

// Round 3
// 128.245 us; speedup vs baseline: 2.3624x; 1.1158x over previous
//
#include <hip/hip_runtime.h>
#include <math.h>

#define BATCH 256
#define CLS 500
#define ATT_DIM_ 1024
#define IMG_DIM_ 1024
#define ATT_HC_ 256
#define HIDDEN_ 1024
#define T_TEMP_ 10.0f
#define THRESH_ 0.86602540378443864676f
#define NEGV -9.0e15f

// ---------------- generic f32 tiled GEMM with grid split-K ----------------
// C/partial[M,N]; BM=BN=64, BK=16, 256 threads, 4x4 micro-tile per thread.
// blockIdx.z = K-split index; klen = K elements per split.
// If gridDim.z>1, writes partial at C + z*M*N (bias must be nullptr; reduce adds it).
__global__ __launch_bounds__(256) void gemm_f32(
    const float* __restrict__ A, const float* __restrict__ B,
    const float* __restrict__ bias, float* __restrict__ C,
    int M, int N, int K, int klen)
{
    __shared__ float As[64][20];   // padded: breaks bank alias
    __shared__ float Bs[16][64];
    const int t  = threadIdx.x;
    const int tb = t >> 4, tc = t & 15;
    const int m0 = blockIdx.x * 64, n0 = blockIdx.y * 64;
    const int k0 = blockIdx.z * klen;

    const int arow  = t >> 2;          // 0..63
    const int acol4 = (t & 3) * 4;     // 0,4,8,12
    const int brow  = t >> 4;          // 0..15
    const int bcol4 = (t & 15) * 4;    // 0..60

    float* Cw = C + (gridDim.z > 1 ? (size_t)blockIdx.z * M * N : 0);

    float acc[4][4] = {};

    for (int kb = k0; kb < k0 + klen; kb += 16) {
        float4 av = make_float4(0.f, 0.f, 0.f, 0.f);
        if (m0 + arow < M)
            av = *(const float4*)&A[(size_t)(m0 + arow) * K + kb + acol4];
        *(float4*)&As[arow][acol4] = av;

        float4 bv = *(const float4*)&B[(size_t)(kb + brow) * N + n0 + bcol4];
        *(float4*)&Bs[brow][bcol4] = bv;
        __syncthreads();

        #pragma unroll
        for (int k4 = 0; k4 < 4; ++k4) {
            float4 a0 = *(float4*)&As[tb +  0][k4 * 4];
            float4 a1 = *(float4*)&As[tb + 16][k4 * 4];
            float4 a2 = *(float4*)&As[tb + 32][k4 * 4];
            float4 a3 = *(float4*)&As[tb + 48][k4 * 4];
            #pragma unroll
            for (int e = 0; e < 4; ++e) {
                const int k = k4 * 4 + e;
                float b0 = Bs[k][tc +  0];
                float b1 = Bs[k][tc + 16];
                float b2 = Bs[k][tc + 32];
                float b3 = Bs[k][tc + 48];
                float a_[4] = { (&a0.x)[e], (&a1.x)[e], (&a2.x)[e], (&a3.x)[e] };
                #pragma unroll
                for (int i = 0; i < 4; ++i) {
                    acc[i][0] += a_[i] * b0;
                    acc[i][1] += a_[i] * b1;
                    acc[i][2] += a_[i] * b2;
                    acc[i][3] += a_[i] * b3;
                }
            }
        }
        __syncthreads();
    }

    #pragma unroll
    for (int i = 0; i < 4; ++i) {
        const int m = m0 + tb + 16 * i;
        if (m >= M) continue;
        #pragma unroll
        for (int j = 0; j < 4; ++j) {
            const int n = n0 + tc + 16 * j;
            float v = acc[i][j];
            if (bias) v += bias[n];
            Cw[(size_t)m * N + n] = v;
        }
    }
}

// ---------------- reduce split-K partials (+bias) ----------------
__global__ __launch_bounds__(256) void reduce_splitk(
    const float* __restrict__ part, const float* __restrict__ bias,
    float* __restrict__ C, int MN, int N, int ks)
{
    const int idx = blockIdx.x * 256 + threadIdx.x;
    if (idx >= MN) return;
    float s = bias ? bias[idx % N] : 0.f;
    for (int i = 0; i < ks; ++i) s += part[(size_t)i * MN + idx];
    C[idx] = s;
}

// ---------------- row-normalize g[500,256] in place ----------------
__global__ __launch_bounds__(256) void row_normalize(float* __restrict__ g)
{
    const int c = blockIdx.x, t = threadIdx.x;
    float v  = g[(size_t)c * 256 + t];
    float ss = v * v;
    #pragma unroll
    for (int off = 32; off >= 1; off >>= 1) ss += __shfl_down(ss, off);
    __shared__ float red[4];
    const int wave = t >> 6, lane = t & 63;
    if (lane == 0) red[wave] = ss;
    __syncthreads();
    const float tot = red[0] + red[1] + red[2] + red[3];
    const float rn  = 1.f / sqrtf(tot);
    g[(size_t)c * 256 + t] = v * rn;
}

// ---------------- sim = gn @ gn^T : C[M,N]=A[M,K]·B[N,K]^T ----------------
// 32x32 tile, BK=32, 256 threads, 2x2 micro-tile. Coalesced float4 loads of BOTH
// operands (row-major); fixes the stride-1024 uncoalesced pattern of round-2.
__global__ __launch_bounds__(256) void gemm_tn32(
    const float* __restrict__ A, const float* __restrict__ B,
    float* __restrict__ C, int M, int N, int K)
{
    __shared__ float As[32][36];   // +4 pad
    __shared__ float Bs[32][36];
    const int t  = threadIdx.x;
    const int tr = t >> 4, tc = t & 15;
    const int m0 = blockIdx.x * 32, n0 = blockIdx.y * 32;
    const int lrow = t >> 3;         // 0..31
    const int lcol = (t & 7) * 4;    // 0..28

    float acc[2][2] = {};

    for (int kb = 0; kb < K; kb += 32) {
        float4 av = make_float4(0.f, 0.f, 0.f, 0.f);
        float4 bv = make_float4(0.f, 0.f, 0.f, 0.f);
        if (m0 + lrow < M) av = *(const float4*)&A[(size_t)(m0 + lrow) * K + kb + lcol];
        if (n0 + lrow < N) bv = *(const float4*)&B[(size_t)(n0 + lrow) * K + kb + lcol];
        *(float4*)&As[lrow][lcol] = av;
        *(float4*)&Bs[lrow][lcol] = bv;
        __syncthreads();

        #pragma unroll
        for (int k = 0; k < 32; ++k) {
            const float a0 = As[tr][k],      a1 = As[tr + 16][k];
            const float b0 = Bs[tc][k],      b1 = Bs[tc + 16][k];
            acc[0][0] += a0 * b0;  acc[0][1] += a0 * b1;
            acc[1][0] += a1 * b0;  acc[1][1] += a1 * b1;
        }
        __syncthreads();
    }

    #pragma unroll
    for (int i = 0; i < 2; ++i) {
        const int m = m0 + tr + 16 * i;
        if (m >= M) continue;
        #pragma unroll
        for (int j = 0; j < 2; ++j) {
            const int n = n0 + tc + 16 * j;
            if (n < N) C[(size_t)m * N + n] = acc[i][j];
        }
    }
}

// ---------------- masked softmax + sparse attention @ attributes ----------------
// One block per class row c; reads precomputed sim row (coalesced).
__global__ __launch_bounds__(256) void softmax_att_kernel(
    const float* __restrict__ sim, const float* __restrict__ attrs,
    float* __restrict__ att_outs)
{
    const int c = blockIdx.x, t = threadIdx.x;
    __shared__ float p_s[512];
    __shared__ float redm[4];
    __shared__ float reds[4];

    const float d0 = sim[(size_t)c * CLS + t];
    const float d1 = (t + 256 < CLS) ? sim[(size_t)c * CLS + t + 256] : NEGV;

    float vmax = fmaxf((d0 > THRESH_) ? d0 : NEGV, (d1 > THRESH_) ? d1 : NEGV);
    #pragma unroll
    for (int off = 32; off >= 1; off >>= 1) vmax = fmaxf(vmax, __shfl_down(vmax, off));
    const int wave = t >> 6, lane = t & 63;
    if (lane == 0) redm[wave] = vmax;
    __syncthreads();
    const float m = fmaxf(fmaxf(redm[0], redm[1]), fmaxf(redm[2], redm[3]));

    const float p0 = (d0 > THRESH_) ? expf(T_TEMP_ * (d0 - m)) : 0.f;
    const float p1 = (d1 > THRESH_) ? expf(T_TEMP_ * (d1 - m)) : 0.f;
    p_s[t] = p0;
    p_s[t + 256] = p1;
    float vsum = p0 + p1;
    #pragma unroll
    for (int off = 32; off >= 1; off >>= 1) vsum += __shfl_down(vsum, off);
    if (lane == 0) reds[wave] = vsum;
    __syncthreads();   // also orders p_s writes before the scan
    const float inv = 1.f / (reds[0] + reds[1] + reds[2] + reds[3]);

    // attention row is exactly sparse (masked -> exp underflows to 0 in ref too)
    float acc[4] = {0.f, 0.f, 0.f, 0.f};
    for (int c2 = 0; c2 < CLS; ++c2) {
        const float pv = p_s[c2];
        if (pv > 0.f) {
            const float* ar = &attrs[(size_t)c2 * 1024 + t];
            #pragma unroll
            for (int j = 0; j < 4; ++j) acc[j] += pv * ar[256 * j];
        }
    }
    #pragma unroll
    for (int j = 0; j < 4; ++j)
        att_outs[(size_t)c * 1024 + t + 256 * j] = acc[j] * inv;
}

// ---------------- fused relu-reduction partials ----------------
// partial[nh][b][c] = sum_{h in chunk nh} relu(img_h[b,h]+sem_h[c,h]) * fc_w[h]
__global__ __launch_bounds__(256) void fused_out_partial(
    const float* __restrict__ img_h, const float* __restrict__ sem_h,
    const float* __restrict__ fc_w, float* __restrict__ partial, int h_per)
{
    __shared__ float imgs[64][68];
    __shared__ float sems[64][68];
    __shared__ float fcs[128];

    const int t  = threadIdx.x;
    const int tb = t >> 4, tc = t & 15;
    const int b0 = blockIdx.x * 64, c0 = blockIdx.y * 64;
    const int h0 = blockIdx.z * h_per;

    if (t < (h_per >> 2)) *(float4*)&fcs[t * 4] = *(const float4*)&fc_w[h0 + t * 4];

    float acc[4][4] = {};

    for (int hs = 0; hs < (h_per >> 6); ++hs) {
        const int hb = h0 + hs * 64;
        #pragma unroll
        for (int i = 0; i < 4; ++i) {
            const int row = (t >> 4) + 16 * i;
            const int col = (t & 15) * 4;
            *(float4*)&imgs[row][col] =
                *(const float4*)&img_h[(size_t)(b0 + row) * 1024 + hb + col];
            float4 sv = make_float4(0.f, 0.f, 0.f, 0.f);
            if (c0 + row < CLS)
                sv = *(const float4*)&sem_h[(size_t)(c0 + row) * 1024 + hb + col];
            *(float4*)&sems[row][col] = sv;
        }
        __syncthreads();

        #pragma unroll
        for (int h4 = 0; h4 < 16; ++h4) {
            float4 ia[4], sa[4];
            #pragma unroll
            for (int i = 0; i < 4; ++i) ia[i] = *(float4*)&imgs[tb + 16 * i][h4 * 4];
            #pragma unroll
            for (int j = 0; j < 4; ++j) sa[j] = *(float4*)&sems[tc + 16 * j][h4 * 4];
            #pragma unroll
            for (int e = 0; e < 4; ++e) {
                const float w = fcs[hs * 64 + h4 * 4 + e];
                #pragma unroll
                for (int i = 0; i < 4; ++i) {
                    const float iv = (&ia[i].x)[e];
                    #pragma unroll
                    for (int j = 0; j < 4; ++j) {
                        const float sv = (&sa[j].x)[e];
                        acc[i][j] += fmaxf(iv + sv, 0.f) * w;
                    }
                }
            }
        }
        __syncthreads();
    }

    const int nh = blockIdx.z;
    #pragma unroll
    for (int i = 0; i < 4; ++i) {
        const int b = b0 + tb + 16 * i;
        #pragma unroll
        for (int j = 0; j < 4; ++j) {
            const int cc = c0 + tc + 16 * j;
            if (cc < CLS)
                partial[((size_t)nh * BATCH + b) * CLS + cc] = acc[i][j];
        }
    }
}

// ---------------- finalize: out[b,c] = fc_b + sum_nh partial ----------------
__global__ __launch_bounds__(256) void finalize_kernel(
    const float* __restrict__ partial, const float* __restrict__ fc_b,
    float* __restrict__ out, int nsplit)
{
    const int idx = blockIdx.x * 256 + threadIdx.x;
    if (idx >= BATCH * CLS) return;
    float s = fc_b[0];
    for (int nh = 0; nh < nsplit; ++nh)
        s += partial[(size_t)nh * BATCH * CLS + idx];
    out[idx] = s;
}

extern "C" void kernel_launch(void* const* d_in, const int* in_sizes, int n_in,
                              void* d_out, int out_size, void* d_ws, size_t ws_size,
                              hipStream_t stream)
{
    const float* image_feats = (const float*)d_in[0];
    const float* attributes  = (const float*)d_in[1];
    const float* att_g       = (const float*)d_in[3];
    const float* img_w       = (const float*)d_in[4];
    const float* sem_w       = (const float*)d_in[5];
    const float* sem_b       = (const float*)d_in[6];
    const float* fc_w        = (const float*)d_in[7];
    const float* fc_b        = (const float*)d_in[8];
    float* out = (float*)d_out;

    char* ws = (char*)d_ws;
    float* gn       = (float*)(ws);              // 500*256*4  = 512000 B
    float* att_outs = (float*)(ws + 0x080000);   // 500*1024*4 = 2048000 B
    float* img_h    = (float*)(ws + 0x280000);   // 256*1024*4 = 1048576 B
    float* sem_h    = (float*)(ws + 0x380000);   // 500*1024*4 = 2048000 B
    float* scratch  = (float*)(ws + 0x580000);   // shared (time-disjoint): split-K
                                                 // partials / sim / out partials

    // guaranteed: ws_size >= 0x580000 + 4,096,000 (round-1/2 footprint passed)
    const size_t avail = ws_size - 0x580000;
    auto pick_ks = [&](size_t mn) {
        int ks = 8;
        while (ks > 1 && (size_t)ks * mn * 4 > avail) ks >>= 1;
        return ks;
    };

    // 1. g = attributes @ att_g   [500,256], K=1024
    {
        const int M = CLS, N = ATT_HC_, K = ATT_DIM_;
        const int ks = pick_ks((size_t)M * N);
        gemm_f32<<<dim3((M + 63) / 64, N / 64, ks), 256, 0, stream>>>(
            attributes, att_g, nullptr, ks == 1 ? gn : scratch, M, N, K, K / ks);
        if (ks > 1)
            reduce_splitk<<<(M * N + 255) / 256, 256, 0, stream>>>(
                scratch, nullptr, gn, M * N, N, ks);
    }
    // 2. row-normalize -> gn
    row_normalize<<<CLS, 256, 0, stream>>>(gn);
    // 3a. sim = gn @ gn^T   [500,500]  (scratch, 1 MB)
    gemm_tn32<<<dim3((CLS + 31) / 32, (CLS + 31) / 32), 256, 0, stream>>>(
        gn, gn, scratch, CLS, CLS, ATT_HC_);
    // 3b. masked softmax + sparse accumulate -> att_outs  [500,1024]
    softmax_att_kernel<<<CLS, 256, 0, stream>>>(scratch, attributes, att_outs);
    // 4. img_h = image_feats @ img_w   [256,1024], K=1024
    {
        const int M = BATCH, N = HIDDEN_, K = IMG_DIM_;
        const int ks = pick_ks((size_t)M * N);
        gemm_f32<<<dim3(M / 64, N / 64, ks), 256, 0, stream>>>(
            image_feats, img_w, nullptr, ks == 1 ? img_h : scratch, M, N, K, K / ks);
        if (ks > 1)
            reduce_splitk<<<(M * N + 255) / 256, 256, 0, stream>>>(
                scratch, nullptr, img_h, M * N, N, ks);
    }
    // 5. sem_h = att_outs @ sem_w + sem_b   [500,1024], K=1024
    {
        const int M = CLS, N = HIDDEN_, K = ATT_DIM_;
        const int ks = pick_ks((size_t)M * N);
        gemm_f32<<<dim3((M + 63) / 64, N / 64, ks), 256, 0, stream>>>(
            att_outs, sem_w, ks == 1 ? sem_b : nullptr, ks == 1 ? sem_h : scratch,
            M, N, K, K / ks);
        if (ks > 1)
            reduce_splitk<<<(M * N + 255) / 256, 256, 0, stream>>>(
                scratch, sem_b, sem_h, M * N, N, ks);
    }
    // 6. fused relu-reduction partials over h-chunks (reuses scratch region)
    {
        const int nh = (avail >= (size_t)16 * BATCH * CLS * 4) ? 16 : 8;
        const int h_per = HIDDEN_ / nh;
        fused_out_partial<<<dim3(BATCH / 64, (CLS + 63) / 64, nh), 256, 0, stream>>>(
            img_h, sem_h, fc_w, scratch, h_per);
        // 7. finalize
        finalize_kernel<<<(BATCH * CLS + 255) / 256, 256, 0, stream>>>(
            scratch, fc_b, out, nh);
    }
}

// Round 4
// 103.711 us; speedup vs baseline: 2.9213x; 1.2366x over previous
//
#include <hip/hip_runtime.h>
#include <math.h>

#define BATCH 256
#define CLS 500
#define HIDDEN_ 1024
#define T_TEMP_ 10.0f
#define THRESH_ 0.86602540378443864676f
#define NEGV -9.0e15f

typedef __attribute__((ext_vector_type(8))) short short8;
typedef __attribute__((ext_vector_type(8))) unsigned short u16x8;
typedef __attribute__((ext_vector_type(4))) float f32x4;

static __device__ __forceinline__ unsigned short f2bf(float x) {
    // round-to-nearest-even f32 -> bf16
    unsigned int u = __builtin_bit_cast(unsigned int, x);
    u += 0x7fff + ((u >> 16) & 1);
    return (unsigned short)(u >> 16);
}
static __device__ __forceinline__ float fel(const float4& v, int j) {
    return (&v.x)[j];
}

// ---------------- bf16 MFMA GEMM (inputs f32, f32 accum) ----------------
// C[M,N] = A @ B   (bt_mode=1: C = A @ B^T, staging B rows like A rows)
// Block tile 64x128, BK=32, 256 threads = 4 waves (2x2 grid of 32x64 wave tiles).
// Row-region split: m-tile bx < a2t0 -> rows from A1 (limit alim1), B1;
//                   else rows (bx-a2t0)*64 from A2 (limit alim2), B2.
// gridDim.z = split-K; klen multiple of 32; partials at C + z*M*N when gridz>1.
__global__ __launch_bounds__(256) void mfma_gemm(
    const float* __restrict__ A1, int alim1,
    const float* __restrict__ A2, int a2t0, int alim2,
    const float* __restrict__ B1, const float* __restrict__ B2,
    float* __restrict__ C, int M, int N, int K, int klen, int bt_mode)
{
    __shared__ unsigned short As[64][40];    // [row][k], pad 32->40 (2-way max)
    __shared__ unsigned short Bs[128][40];   // [n][k] (B column-major in LDS)

    const int t  = threadIdx.x;
    const int bx = blockIdx.x;
    const int n0 = blockIdx.y * 128;
    const int k0 = blockIdx.z * klen;

    const float* A; const float* B; int ar0, alim;
    if (bx < a2t0) { A = A1; B = B1; ar0 = bx * 64;          alim = alim1; }
    else           { A = A2; B = B2; ar0 = (bx - a2t0) * 64; alim = alim2; }

    const int w = t >> 6, lane = t & 63;
    const int wr = w >> 1, wc = w & 1;          // wave tile: rows wr*32, cols wc*64
    const int fr = lane & 15, kg = lane >> 4;   // frag row/col, k-group

    const int as_row = t >> 2, as_kq = t & 3;           // A-stage: 64 rows x 4 k-octets
    const int bs_nc  = (t & 31) * 4, bs_kr = t >> 5;    // B-stage: 32 col-quads x 8 k-quads
    const int bt_row = t >> 1, bt_kq = t & 1;           // BT-stage: 128 rows x 2 k-16s

    f32x4 zero4 = {0.f, 0.f, 0.f, 0.f};
    f32x4 acc[2][4];
    #pragma unroll
    for (int i = 0; i < 2; ++i)
        #pragma unroll
        for (int j = 0; j < 4; ++j) acc[i][j] = zero4;

    for (int kb = k0; kb < k0 + klen; kb += 32) {
        // ---- stage A (f32 -> bf16), As[row][k]
        {
            const int gr = ar0 + as_row;
            float4 v0 = make_float4(0.f, 0.f, 0.f, 0.f);
            float4 v1 = make_float4(0.f, 0.f, 0.f, 0.f);
            if (gr < alim) {
                const float* p = &A[(size_t)gr * K + kb + as_kq * 8];
                v0 = *(const float4*)p;
                v1 = *(const float4*)(p + 4);
            }
            u16x8 a8;
            a8[0] = f2bf(v0.x); a8[1] = f2bf(v0.y); a8[2] = f2bf(v0.z); a8[3] = f2bf(v0.w);
            a8[4] = f2bf(v1.x); a8[5] = f2bf(v1.y); a8[6] = f2bf(v1.z); a8[7] = f2bf(v1.w);
            *(u16x8*)&As[as_row][as_kq * 8] = a8;
        }
        // ---- stage B
        if (!bt_mode) {
            // B row-major [K,N]: rows kb+bs_kr*4+i, cols n0+bs_nc..+3 -> Bs[n][k]
            const float* p = &B[(size_t)(kb + bs_kr * 4) * N + n0 + bs_nc];
            float4 r0 = *(const float4*)(p);
            float4 r1 = *(const float4*)(p + N);
            float4 r2 = *(const float4*)(p + 2 * N);
            float4 r3 = *(const float4*)(p + 3 * N);
            #pragma unroll
            for (int j = 0; j < 4; ++j) {
                unsigned int lo = (unsigned int)f2bf(fel(r0, j)) | ((unsigned int)f2bf(fel(r1, j)) << 16);
                unsigned int hi = (unsigned int)f2bf(fel(r2, j)) | ((unsigned int)f2bf(fel(r3, j)) << 16);
                uint2 u2; u2.x = lo; u2.y = hi;
                *(uint2*)&Bs[bs_nc + j][bs_kr * 4] = u2;
            }
        } else {
            // B^T mode: stage B rows (n0+bt_row) as columns; guard vs N
            const int gr = n0 + bt_row;
            float4 v0 = make_float4(0.f,0.f,0.f,0.f), v1 = v0, v2 = v0, v3 = v0;
            if (gr < N) {
                const float* p = &B[(size_t)gr * K + kb + bt_kq * 16];
                v0 = *(const float4*)(p);
                v1 = *(const float4*)(p + 4);
                v2 = *(const float4*)(p + 8);
                v3 = *(const float4*)(p + 12);
            }
            u16x8 b8;
            b8[0] = f2bf(v0.x); b8[1] = f2bf(v0.y); b8[2] = f2bf(v0.z); b8[3] = f2bf(v0.w);
            b8[4] = f2bf(v1.x); b8[5] = f2bf(v1.y); b8[6] = f2bf(v1.z); b8[7] = f2bf(v1.w);
            *(u16x8*)&Bs[bt_row][bt_kq * 16] = b8;
            u16x8 c8;
            c8[0] = f2bf(v2.x); c8[1] = f2bf(v2.y); c8[2] = f2bf(v2.z); c8[3] = f2bf(v2.w);
            c8[4] = f2bf(v3.x); c8[5] = f2bf(v3.y); c8[6] = f2bf(v3.z); c8[7] = f2bf(v3.w);
            *(u16x8*)&Bs[bt_row][bt_kq * 16 + 8] = c8;
        }
        __syncthreads();

        // ---- fragments + 8 MFMAs (one 32-K step)
        short8 af[2], bf[4];
        #pragma unroll
        for (int i = 0; i < 2; ++i)
            af[i] = *(short8*)&As[wr * 32 + i * 16 + fr][kg * 8];
        #pragma unroll
        for (int j = 0; j < 4; ++j)
            bf[j] = *(short8*)&Bs[wc * 64 + j * 16 + fr][kg * 8];
        #pragma unroll
        for (int i = 0; i < 2; ++i)
            #pragma unroll
            for (int j = 0; j < 4; ++j)
                acc[i][j] = __builtin_amdgcn_mfma_f32_16x16x32_bf16(
                    af[i], bf[j], acc[i][j], 0, 0, 0);
        __syncthreads();
    }

    // ---- epilogue: D col = lane&15, row = (lane>>4)*4 + reg (m89-verified)
    float* Cw = C + (gridDim.z > 1 ? (size_t)blockIdx.z * M * N : 0);
    const int orow0 = bx * 64 + wr * 32, ocol0 = n0 + wc * 64;
    #pragma unroll
    for (int i = 0; i < 2; ++i) {
        const int r0 = orow0 + i * 16 + kg * 4;
        #pragma unroll
        for (int j = 0; j < 4; ++j) {
            const int cc = ocol0 + j * 16 + fr;
            if (cc >= N) continue;
            #pragma unroll
            for (int r = 0; r < 4; ++r) {
                const int rr = r0 + r;
                if (rr < M) Cw[(size_t)rr * N + cc] = acc[i][j][r];
            }
        }
    }
}

// ---------------- reduce split-K partials (+row-conditional bias) ----------------
__global__ __launch_bounds__(256) void reduce_splitk(
    const float* __restrict__ part, const float* __restrict__ bias, int bias_row0,
    float* __restrict__ C, int MN, int N, int ks)
{
    const int idx = blockIdx.x * 256 + threadIdx.x;
    if (idx >= MN) return;
    float s = 0.f;
    if (bias && (idx / N) >= bias_row0) s = bias[idx % N];
    for (int i = 0; i < ks; ++i) s += part[(size_t)i * MN + idx];
    C[idx] = s;
}

// ---------------- row-normalize g[500,256] in place ----------------
__global__ __launch_bounds__(256) void row_normalize(float* __restrict__ g)
{
    const int c = blockIdx.x, t = threadIdx.x;
    float v  = g[(size_t)c * 256 + t];
    float ss = v * v;
    #pragma unroll
    for (int off = 32; off >= 1; off >>= 1) ss += __shfl_down(ss, off);
    __shared__ float red[4];
    const int wave = t >> 6, lane = t & 63;
    if (lane == 0) red[wave] = ss;
    __syncthreads();
    const float tot = red[0] + red[1] + red[2] + red[3];
    const float rn  = 1.f / sqrtf(tot);
    g[(size_t)c * 256 + t] = v * rn;
}

// ---------------- masked softmax + sparse attention @ attributes ----------------
__global__ __launch_bounds__(256) void softmax_att_kernel(
    const float* __restrict__ sim, const float* __restrict__ attrs,
    float* __restrict__ att_outs)
{
    const int c = blockIdx.x, t = threadIdx.x;
    __shared__ float p_s[512];
    __shared__ float redm[4];
    __shared__ float reds[4];

    const float d0 = sim[(size_t)c * CLS + t];
    const float d1 = (t + 256 < CLS) ? sim[(size_t)c * CLS + t + 256] : NEGV;

    float vmax = fmaxf((d0 > THRESH_) ? d0 : NEGV, (d1 > THRESH_) ? d1 : NEGV);
    #pragma unroll
    for (int off = 32; off >= 1; off >>= 1) vmax = fmaxf(vmax, __shfl_down(vmax, off));
    const int wave = t >> 6, lane = t & 63;
    if (lane == 0) redm[wave] = vmax;
    __syncthreads();
    const float m = fmaxf(fmaxf(redm[0], redm[1]), fmaxf(redm[2], redm[3]));

    const float p0 = (d0 > THRESH_) ? expf(T_TEMP_ * (d0 - m)) : 0.f;
    const float p1 = (d1 > THRESH_) ? expf(T_TEMP_ * (d1 - m)) : 0.f;
    p_s[t] = p0;
    p_s[t + 256] = p1;
    float vsum = p0 + p1;
    #pragma unroll
    for (int off = 32; off >= 1; off >>= 1) vsum += __shfl_down(vsum, off);
    if (lane == 0) reds[wave] = vsum;
    __syncthreads();
    const float inv = 1.f / (reds[0] + reds[1] + reds[2] + reds[3]);

    float acc[4] = {0.f, 0.f, 0.f, 0.f};
    for (int c2 = 0; c2 < CLS; ++c2) {
        const float pv = p_s[c2];
        if (pv > 0.f) {
            const float* ar = &attrs[(size_t)c2 * 1024 + t];
            #pragma unroll
            for (int j = 0; j < 4; ++j) acc[j] += pv * ar[256 * j];
        }
    }
    #pragma unroll
    for (int j = 0; j < 4; ++j)
        att_outs[(size_t)c * 1024 + t + 256 * j] = acc[j] * inv;
}

// ---------------- fused relu-reduction partials ----------------
__global__ __launch_bounds__(256) void fused_out_partial(
    const float* __restrict__ img_h, const float* __restrict__ sem_h,
    const float* __restrict__ fc_w, float* __restrict__ partial, int h_per)
{
    __shared__ float imgs[64][68];
    __shared__ float sems[64][68];
    __shared__ float fcs[128];

    const int t  = threadIdx.x;
    const int tb = t >> 4, tc = t & 15;
    const int b0 = blockIdx.x * 64, c0 = blockIdx.y * 64;
    const int h0 = blockIdx.z * h_per;

    if (t < (h_per >> 2)) *(float4*)&fcs[t * 4] = *(const float4*)&fc_w[h0 + t * 4];

    float acc[4][4] = {};

    for (int hs = 0; hs < (h_per >> 6); ++hs) {
        const int hb = h0 + hs * 64;
        #pragma unroll
        for (int i = 0; i < 4; ++i) {
            const int row = (t >> 4) + 16 * i;
            const int col = (t & 15) * 4;
            *(float4*)&imgs[row][col] =
                *(const float4*)&img_h[(size_t)(b0 + row) * 1024 + hb + col];
            float4 sv = make_float4(0.f, 0.f, 0.f, 0.f);
            if (c0 + row < CLS)
                sv = *(const float4*)&sem_h[(size_t)(c0 + row) * 1024 + hb + col];
            *(float4*)&sems[row][col] = sv;
        }
        __syncthreads();

        #pragma unroll
        for (int h4 = 0; h4 < 16; ++h4) {
            float4 ia[4], sa[4];
            #pragma unroll
            for (int i = 0; i < 4; ++i) ia[i] = *(float4*)&imgs[tb + 16 * i][h4 * 4];
            #pragma unroll
            for (int j = 0; j < 4; ++j) sa[j] = *(float4*)&sems[tc + 16 * j][h4 * 4];
            #pragma unroll
            for (int e = 0; e < 4; ++e) {
                const float w2 = fcs[hs * 64 + h4 * 4 + e];
                #pragma unroll
                for (int i = 0; i < 4; ++i) {
                    const float iv = (&ia[i].x)[e];
                    #pragma unroll
                    for (int j = 0; j < 4; ++j) {
                        const float sv = (&sa[j].x)[e];
                        acc[i][j] += fmaxf(iv + sv, 0.f) * w2;
                    }
                }
            }
        }
        __syncthreads();
    }

    const int nh = blockIdx.z;
    #pragma unroll
    for (int i = 0; i < 4; ++i) {
        const int b = b0 + tb + 16 * i;
        #pragma unroll
        for (int j = 0; j < 4; ++j) {
            const int cc = c0 + tc + 16 * j;
            if (cc < CLS)
                partial[((size_t)nh * BATCH + b) * CLS + cc] = acc[i][j];
        }
    }
}

// ---------------- finalize ----------------
__global__ __launch_bounds__(256) void finalize_kernel(
    const float* __restrict__ partial, const float* __restrict__ fc_b,
    float* __restrict__ out, int nsplit)
{
    const int idx = blockIdx.x * 256 + threadIdx.x;
    if (idx >= BATCH * CLS) return;
    float s = fc_b[0];
    for (int nh = 0; nh < nsplit; ++nh)
        s += partial[(size_t)nh * BATCH * CLS + idx];
    out[idx] = s;
}

extern "C" void kernel_launch(void* const* d_in, const int* in_sizes, int n_in,
                              void* d_out, int out_size, void* d_ws, size_t ws_size,
                              hipStream_t stream)
{
    const float* image_feats = (const float*)d_in[0];
    const float* attributes  = (const float*)d_in[1];
    const float* att_g       = (const float*)d_in[3];
    const float* img_w       = (const float*)d_in[4];
    const float* sem_w       = (const float*)d_in[5];
    const float* sem_b       = (const float*)d_in[6];
    const float* fc_w        = (const float*)d_in[7];
    const float* fc_b        = (const float*)d_in[8];
    float* out = (float*)d_out;

    char* ws = (char*)d_ws;
    float* g       = (float*)(ws);              // 500*256*4  = 512000 B
    float* att_outs= (float*)(ws + 0x080000);   // 500*1024*4 = 2048000 B
    float* hid     = (float*)(ws + 0x280000);   // 756*1024*4 = 3096576 B (img rows 0..255, sem 256..755)
    float* scratch = (float*)(ws + 0x580000);   // time-disjoint: g-partials / sim / hid-partials / out-partials

    const size_t avail = ws_size - 0x580000;    // guaranteed >= 4,096,000 (rounds 1-3 passed)
    const int BIG = 1 << 20;

    // 1. g = attributes @ att_g   [500,256], K=1024, split-K 8 (partials = 4,096,000 B exactly)
    mfma_gemm<<<dim3(8, 2, 8), 256, 0, stream>>>(
        attributes, 500, nullptr, BIG, 0, att_g, att_g,
        scratch, CLS, 256, 1024, 128, 0);
    reduce_splitk<<<(CLS * 256 + 255) / 256, 256, 0, stream>>>(
        scratch, nullptr, 0, g, CLS * 256, 256, 8);

    // 2. row-normalize g -> gn (in place)
    row_normalize<<<CLS, 256, 0, stream>>>(g);

    // 3a. sim = gn @ gn^T   [500,500] -> scratch (1 MB), single-shot (K=256)
    mfma_gemm<<<dim3(8, 4, 1), 256, 0, stream>>>(
        g, 500, nullptr, BIG, 0, g, g,
        scratch, CLS, CLS, 256, 256, 1);
    // 3b. masked softmax + sparse accumulate -> att_outs
    softmax_att_kernel<<<CLS, 256, 0, stream>>>(scratch, attributes, att_outs);

    // 4+5. hid[756,1024]: rows 0..255 = image_feats@img_w, rows 256..755 = att_outs@sem_w (+sem_b)
    {
        const size_t mn = (size_t)756 * 1024;
        int ks = 4;
        while (ks > 1 && (size_t)ks * mn * 4 > avail) ks >>= 1;
        mfma_gemm<<<dim3(12, 8, ks), 256, 0, stream>>>(
            image_feats, 256, att_outs, 4, 500, img_w, sem_w,
            scratch, 756, 1024, 1024, 1024 / ks, 0);
        reduce_splitk<<<(int)((mn + 255) / 256), 256, 0, stream>>>(
            scratch, sem_b, 256, hid, (int)mn, 1024, ks);
    }

    // 6. fused relu-reduction partials
    {
        const int nh = (avail >= (size_t)16 * BATCH * CLS * 4) ? 16 : 8;
        fused_out_partial<<<dim3(BATCH / 64, (CLS + 63) / 64, nh), 256, 0, stream>>>(
            hid, hid + (size_t)256 * 1024, fc_w, scratch, HIDDEN_ / nh);
        finalize_kernel<<<(BATCH * CLS + 255) / 256, 256, 0, stream>>>(
            scratch, fc_b, out, nh);
    }
}

// Round 5
// 68.112 us; speedup vs baseline: 4.4481x; 1.5227x over previous
//
#include <hip/hip_runtime.h>
#include <math.h>

#define BATCH 256
#define CLS 500
#define HIDDEN_ 1024
#define T_TEMP_ 10.0f
#define THRESH_ 0.86602540378443864676f
#define NEGV -9.0e15f

typedef __attribute__((ext_vector_type(8))) short short8;
typedef __attribute__((ext_vector_type(8))) unsigned short u16x8;
typedef __attribute__((ext_vector_type(4))) float f32x4;

static __device__ __forceinline__ unsigned short f2bf(float x) {
    // round-to-nearest-even f32 -> bf16
    unsigned int u = __builtin_bit_cast(unsigned int, x);
    u += 0x7fff + ((u >> 16) & 1);
    return (unsigned short)(u >> 16);
}
static __device__ __forceinline__ u16x8 pack8(const float4& a, const float4& b) {
    u16x8 o;
    o[0] = f2bf(a.x); o[1] = f2bf(a.y); o[2] = f2bf(a.z); o[3] = f2bf(a.w);
    o[4] = f2bf(b.x); o[5] = f2bf(b.y); o[6] = f2bf(b.z); o[7] = f2bf(b.w);
    return o;
}

// ---------------- one-time convert / transpose to bf16 ----------------
// blocks [0,250): attributes cast; [250,378): image_feats cast;
// [378,442): att_g^T; [442,698): img_w^T; [698,954): sem_w^T.
__global__ __launch_bounds__(256) void convert_kernel(
    const float* __restrict__ attrs, const float* __restrict__ imgf,
    const float* __restrict__ attg, const float* __restrict__ imgw,
    const float* __restrict__ semw,
    unsigned short* __restrict__ attrs_bf, unsigned short* __restrict__ imgf_bf,
    unsigned short* __restrict__ attgT, unsigned short* __restrict__ imgwT,
    unsigned short* __restrict__ semwT)
{
    __shared__ unsigned short tb[64][72];   // transpose tile, +8 pad
    const int t = threadIdx.x;
    int bid = blockIdx.x;

    if (bid < 378) {  // plain casts
        const float* s; unsigned short* d; int idx;
        if (bid < 250) { s = attrs; d = attrs_bf; idx = bid * 2048 + t * 8; }
        else           { s = imgf;  d = imgf_bf;  idx = (bid - 250) * 2048 + t * 8; }
        float4 v0 = *(const float4*)&s[idx];
        float4 v1 = *(const float4*)&s[idx + 4];
        *(u16x8*)&d[idx] = pack8(v0, v1);
        return;
    }
    bid -= 378;
    const float* s; unsigned short* d; int Csz;
    if (bid < 64)       { s = attg; d = attgT; Csz = 256; }
    else if (bid < 320) { bid -= 64;  s = imgw; d = imgwT; Csz = 1024; }
    else                { bid -= 320; s = semw; d = semwT; Csz = 1024; }
    const int tiles_c = Csz >> 6;
    const int tr = bid / tiles_c, tc = bid % tiles_c;
    {   // load 64x64 f32 tile coalesced, convert
        const int r = t >> 2, cq = (t & 3) * 16;
        const float* p = &s[(size_t)(tr * 64 + r) * Csz + tc * 64 + cq];
        float4 v0 = *(const float4*)(p);
        float4 v1 = *(const float4*)(p + 4);
        float4 v2 = *(const float4*)(p + 8);
        float4 v3 = *(const float4*)(p + 12);
        *(u16x8*)&tb[r][cq]     = pack8(v0, v1);
        *(u16x8*)&tb[r][cq + 8] = pack8(v2, v3);
    }
    __syncthreads();
    {   // store transposed, coalesced bf16
        const int c = t >> 2, r0 = (t & 3) * 16;
        u16x8 o0, o1;
        #pragma unroll
        for (int i = 0; i < 8; ++i) { o0[i] = tb[r0 + i][c]; o1[i] = tb[r0 + 8 + i][c]; }
        unsigned short* q = &d[(size_t)(tc * 64 + c) * 1024 + tr * 64 + r0];
        *(u16x8*)q = o0;
        *(u16x8*)(q + 8) = o1;
    }
}

// ---------------- unified bf16 MFMA GEMM: C[M,N] = A[M,K] @ B[N,K]^T ----------------
// A row-major bf16 [M][K]; B given as [N][K] bf16 (pre-transposed weights).
// Block tile 64x128, BK=32, 256 threads = 4 waves (2x2 of 32x64 wave tiles).
// Row-region split for fused dispatches (A1 rows then A2 rows, B switches with region).
// gridDim.z = split-K; partials at C + z*M*N when gridDim.z > 1. Register prefetch.
__global__ __launch_bounds__(256) void mfma_gemm_bf(
    const unsigned short* __restrict__ A1, int alim1,
    const unsigned short* __restrict__ A2, int a2t0, int alim2,
    const unsigned short* __restrict__ B1, const unsigned short* __restrict__ B2,
    float* __restrict__ C, int M, int N, int K, int klen)
{
    __shared__ unsigned short As[64][40];    // [row][k], +8 pad
    __shared__ unsigned short Bs[128][40];   // [n][k]

    const int t  = threadIdx.x;
    const int bx = blockIdx.x;
    const int n0 = blockIdx.y * 128;
    const int k0 = blockIdx.z * klen;

    const unsigned short* A; const unsigned short* B; int ar0, alim;
    if (bx < a2t0) { A = A1; B = B1; ar0 = bx * 64;          alim = alim1; }
    else           { A = A2; B = B2; ar0 = (bx - a2t0) * 64; alim = alim2; }

    const int w = t >> 6, lane = t & 63;
    const int wr = w >> 1, wc = w & 1;
    const int fr = lane & 15, kg = lane >> 4;

    const int a_row = t >> 2, a_k = (t & 3) * 8;    // 64 rows x 4 k-octets
    const int b_row = t >> 1, b_k = (t & 1) * 16;   // 128 rows x 2 k-16s
    const int gra = ar0 + a_row;
    const int grb = n0 + b_row;
    const bool va = gra < alim;
    const bool vb = grb < N;
    const size_t abase = (size_t)gra * K + a_k;
    const size_t bbase = (size_t)grb * K + b_k;

    u16x8 zz = {0,0,0,0,0,0,0,0};
    u16x8 pa = zz, pb0 = zz, pb1 = zz;
    if (va) pa = *(const u16x8*)&A[abase + k0];
    if (vb) { pb0 = *(const u16x8*)&B[bbase + k0]; pb1 = *(const u16x8*)&B[bbase + k0 + 8]; }

    f32x4 zero4 = {0.f, 0.f, 0.f, 0.f};
    f32x4 acc[2][4];
    #pragma unroll
    for (int i = 0; i < 2; ++i)
        #pragma unroll
        for (int j = 0; j < 4; ++j) acc[i][j] = zero4;

    for (int kb = k0; kb < k0 + klen; kb += 32) {
        *(u16x8*)&As[a_row][a_k] = pa;
        *(u16x8*)&Bs[b_row][b_k] = pb0;
        *(u16x8*)&Bs[b_row][b_k + 8] = pb1;
        __syncthreads();

        const int kn = kb + 32;           // register prefetch of next tile
        if (kn < k0 + klen) {
            if (va) pa = *(const u16x8*)&A[abase + kn];
            if (vb) { pb0 = *(const u16x8*)&B[bbase + kn]; pb1 = *(const u16x8*)&B[bbase + kn + 8]; }
        }

        short8 af[2], bfr[4];
        #pragma unroll
        for (int i = 0; i < 2; ++i)
            af[i] = *(short8*)&As[wr * 32 + i * 16 + fr][kg * 8];
        #pragma unroll
        for (int j = 0; j < 4; ++j)
            bfr[j] = *(short8*)&Bs[wc * 64 + j * 16 + fr][kg * 8];
        #pragma unroll
        for (int i = 0; i < 2; ++i)
            #pragma unroll
            for (int j = 0; j < 4; ++j)
                acc[i][j] = __builtin_amdgcn_mfma_f32_16x16x32_bf16(
                    af[i], bfr[j], acc[i][j], 0, 0, 0);
        __syncthreads();
    }

    // epilogue: D col = lane&15, row = (lane>>4)*4 + reg
    float* Cw = C + (gridDim.z > 1 ? (size_t)blockIdx.z * M * N : 0);
    const int orow0 = bx * 64 + wr * 32, ocol0 = n0 + wc * 64;
    #pragma unroll
    for (int i = 0; i < 2; ++i) {
        const int r0 = orow0 + i * 16 + kg * 4;
        #pragma unroll
        for (int j = 0; j < 4; ++j) {
            const int cc = ocol0 + j * 16 + fr;
            if (cc >= N) continue;
            #pragma unroll
            for (int r = 0; r < 4; ++r) {
                const int rr = r0 + r;
                if (rr < M) Cw[(size_t)rr * N + cc] = acc[i][j][r];
            }
        }
    }
}

// ---------------- reduce 8 split-K partials + row-normalize -> gn bf16 ----------------
__global__ __launch_bounds__(256) void reduce_norm_kernel(
    const float* __restrict__ part, unsigned short* __restrict__ gn_bf)
{
    const int c = blockIdx.x, t = threadIdx.x;
    float v = 0.f;
    #pragma unroll
    for (int z = 0; z < 8; ++z) v += part[(size_t)z * (CLS * 256) + c * 256 + t];
    float ss = v * v;
    #pragma unroll
    for (int off = 32; off >= 1; off >>= 1) ss += __shfl_down(ss, off);
    __shared__ float red[4];
    const int wave = t >> 6, lane = t & 63;
    if (lane == 0) red[wave] = ss;
    __syncthreads();
    const float tot = red[0] + red[1] + red[2] + red[3];
    const float rn  = 1.f / sqrtf(tot);
    gn_bf[c * 256 + t] = f2bf(v * rn);
}

// ---------------- masked softmax + sparse attention @ attributes (bf16 out) ----------------
__global__ __launch_bounds__(256) void softmax_att_kernel(
    const float* __restrict__ sim, const float* __restrict__ attrs,
    unsigned short* __restrict__ att_outs)
{
    const int c = blockIdx.x, t = threadIdx.x;
    __shared__ float p_s[512];
    __shared__ float redm[4];
    __shared__ float reds[4];

    const float d0 = sim[(size_t)c * CLS + t];
    const float d1 = (t + 256 < CLS) ? sim[(size_t)c * CLS + t + 256] : NEGV;

    float vmax = fmaxf((d0 > THRESH_) ? d0 : NEGV, (d1 > THRESH_) ? d1 : NEGV);
    #pragma unroll
    for (int off = 32; off >= 1; off >>= 1) vmax = fmaxf(vmax, __shfl_down(vmax, off));
    const int wave = t >> 6, lane = t & 63;
    if (lane == 0) redm[wave] = vmax;
    __syncthreads();
    const float m = fmaxf(fmaxf(redm[0], redm[1]), fmaxf(redm[2], redm[3]));

    const float p0 = (d0 > THRESH_) ? expf(T_TEMP_ * (d0 - m)) : 0.f;
    const float p1 = (d1 > THRESH_) ? expf(T_TEMP_ * (d1 - m)) : 0.f;
    p_s[t] = p0;
    p_s[t + 256] = p1;
    float vsum = p0 + p1;
    #pragma unroll
    for (int off = 32; off >= 1; off >>= 1) vsum += __shfl_down(vsum, off);
    if (lane == 0) reds[wave] = vsum;
    __syncthreads();   // orders p_s before the scan
    const float inv = 1.f / (reds[0] + reds[1] + reds[2] + reds[3]);

    // ballot-compacted sparse accumulate (rows are exactly sparse)
    float acc[4] = {0.f, 0.f, 0.f, 0.f};
    for (int base = 0; base < 512; base += 64) {
        const float pv_l = p_s[base + lane];
        unsigned long long mask = __ballot(pv_l > 0.f);
        while (mask) {
            const int l = __ffsll((long long)mask) - 1;
            mask &= mask - 1;
            const int c2 = base + l;
            const float pv = p_s[c2];
            const float* ar = &attrs[(size_t)c2 * 1024 + t];
            #pragma unroll
            for (int j = 0; j < 4; ++j) acc[j] += pv * ar[256 * j];
        }
    }
    #pragma unroll
    for (int j = 0; j < 4; ++j)
        att_outs[(size_t)c * 1024 + t + 256 * j] = f2bf(acc[j] * inv);
}

// ---------------- fused relu-reduction (absorbs split-K reduce + sem_b bias) ----------------
// part: f32 [ks][756][1024] (rows 0..255 img_h partials, 256..755 sem_h partials)
// outpart[nh][b][c] = sum_{h in chunk} relu(img_h[b,h]+sem_h[c,h]+sem_b[h]) * fc_w[h]
__global__ __launch_bounds__(256) void fused_out_partial(
    const float* __restrict__ part, int ks, const float* __restrict__ sem_b,
    const float* __restrict__ fc_w, float* __restrict__ outpart, int h_per)
{
    __shared__ float imgs[64][68];
    __shared__ float sems[64][68];
    __shared__ float fcs[128];

    const size_t pstride = (size_t)756 * 1024;
    const int t  = threadIdx.x;
    const int tb = t >> 4, tc = t & 15;
    const int b0 = blockIdx.x * 64, c0 = blockIdx.y * 64;
    const int h0 = blockIdx.z * h_per;

    if (t < (h_per >> 2)) *(float4*)&fcs[t * 4] = *(const float4*)&fc_w[h0 + t * 4];

    float acc[4][4] = {};

    for (int hs = 0; hs < (h_per >> 6); ++hs) {
        const int hb = h0 + hs * 64;
        #pragma unroll
        for (int i = 0; i < 4; ++i) {
            const int row = (t >> 4) + 16 * i;
            const int col = (t & 15) * 4;
            float4 iv = make_float4(0.f, 0.f, 0.f, 0.f);
            const float* pi = &part[(size_t)(b0 + row) * 1024 + hb + col];
            for (int z = 0; z < ks; ++z) {
                float4 vz = *(const float4*)(pi + z * pstride);
                iv.x += vz.x; iv.y += vz.y; iv.z += vz.z; iv.w += vz.w;
            }
            *(float4*)&imgs[row][col] = iv;

            float4 sv = make_float4(0.f, 0.f, 0.f, 0.f);
            if (c0 + row < CLS) {
                const float* ps = &part[(size_t)(256 + c0 + row) * 1024 + hb + col];
                for (int z = 0; z < ks; ++z) {
                    float4 vz = *(const float4*)(ps + z * pstride);
                    sv.x += vz.x; sv.y += vz.y; sv.z += vz.z; sv.w += vz.w;
                }
                float4 bb = *(const float4*)&sem_b[hb + col];
                sv.x += bb.x; sv.y += bb.y; sv.z += bb.z; sv.w += bb.w;
            }
            *(float4*)&sems[row][col] = sv;
        }
        __syncthreads();

        #pragma unroll
        for (int h4 = 0; h4 < 16; ++h4) {
            float4 ia[4], sa[4];
            #pragma unroll
            for (int i = 0; i < 4; ++i) ia[i] = *(float4*)&imgs[tb + 16 * i][h4 * 4];
            #pragma unroll
            for (int j = 0; j < 4; ++j) sa[j] = *(float4*)&sems[tc + 16 * j][h4 * 4];
            #pragma unroll
            for (int e = 0; e < 4; ++e) {
                const float w2 = fcs[hs * 64 + h4 * 4 + e];
                #pragma unroll
                for (int i = 0; i < 4; ++i) {
                    const float iv = (&ia[i].x)[e];
                    #pragma unroll
                    for (int j = 0; j < 4; ++j) {
                        const float sv = (&sa[j].x)[e];
                        acc[i][j] += fmaxf(iv + sv, 0.f) * w2;
                    }
                }
            }
        }
        __syncthreads();
    }

    const int nh = blockIdx.z;
    #pragma unroll
    for (int i = 0; i < 4; ++i) {
        const int b = b0 + tb + 16 * i;
        #pragma unroll
        for (int j = 0; j < 4; ++j) {
            const int cc = c0 + tc + 16 * j;
            if (cc < CLS)
                outpart[((size_t)nh * BATCH + b) * CLS + cc] = acc[i][j];
        }
    }
}

// ---------------- finalize ----------------
__global__ __launch_bounds__(256) void finalize_kernel(
    const float* __restrict__ partial, const float* __restrict__ fc_b,
    float* __restrict__ out, int nsplit)
{
    const int idx = blockIdx.x * 256 + threadIdx.x;
    if (idx >= BATCH * CLS) return;
    float s = fc_b[0];
    for (int nh = 0; nh < nsplit; ++nh)
        s += partial[(size_t)nh * BATCH * CLS + idx];
    out[idx] = s;
}

extern "C" void kernel_launch(void* const* d_in, const int* in_sizes, int n_in,
                              void* d_out, int out_size, void* d_ws, size_t ws_size,
                              hipStream_t stream)
{
    const float* image_feats = (const float*)d_in[0];
    const float* attributes  = (const float*)d_in[1];
    const float* att_g       = (const float*)d_in[3];
    const float* img_w       = (const float*)d_in[4];
    const float* sem_w       = (const float*)d_in[5];
    const float* sem_b       = (const float*)d_in[6];
    const float* fc_w        = (const float*)d_in[7];
    const float* fc_b        = (const float*)d_in[8];
    float* out = (float*)d_out;

    char* ws = (char*)d_ws;
    size_t off = 0;
    auto alloc = [&](size_t b) { size_t o = off; off = (off + b + 255) & ~(size_t)255; return o; };
    const size_t o_attr = alloc((size_t)500 * 1024 * 2);   // attributes bf16
    const size_t o_imgf = alloc((size_t)256 * 1024 * 2);   // image_feats bf16
    const size_t o_attg = alloc((size_t)256 * 1024 * 2);   // att_g^T bf16  [256][1024]
    const size_t o_imgw = alloc((size_t)1024 * 1024 * 2);  // img_w^T bf16  [1024][1024]
    const size_t o_semw = alloc((size_t)1024 * 1024 * 2);  // sem_w^T bf16
    const size_t o_gn   = alloc((size_t)500 * 256 * 2);    // gn bf16
    const size_t o_atto = alloc((size_t)500 * 1024 * 2);   // att_outs bf16
    const size_t o_gp   = alloc((size_t)8 * 500 * 256 * 4);// g partials / sim (time-disjoint)
    const size_t base   = off;

    int ks = 4, nh = 16;   // ws_size ~256 MiB (poison fill = 262144 KB); guard anyway
    while (base + (size_t)ks * 756 * 1024 * 4 + (size_t)nh * BATCH * CLS * 4 + 512 > ws_size) {
        if (ks > 1) ks >>= 1;
        else if (nh > 8) nh = 8;
        else break;
    }
    const size_t o_hidp = alloc((size_t)ks * 756 * 1024 * 4);
    const size_t o_outp = alloc((size_t)nh * BATCH * CLS * 4);
    (void)o_outp;

    unsigned short* attr_bf = (unsigned short*)(ws + o_attr);
    unsigned short* imgf_bf = (unsigned short*)(ws + o_imgf);
    unsigned short* attgT   = (unsigned short*)(ws + o_attg);
    unsigned short* imgwT   = (unsigned short*)(ws + o_imgw);
    unsigned short* semwT   = (unsigned short*)(ws + o_semw);
    unsigned short* gn_bf   = (unsigned short*)(ws + o_gn);
    unsigned short* atto_bf = (unsigned short*)(ws + o_atto);
    float* gpart_sim        = (float*)(ws + o_gp);
    float* hidP             = (float*)(ws + o_hidp);
    float* outP             = (float*)(ws + o_outp);

    // K0: convert + transpose everything to bf16 once
    convert_kernel<<<954, 256, 0, stream>>>(
        attributes, image_feats, att_g, img_w, sem_w,
        attr_bf, imgf_bf, attgT, imgwT, semwT);

    // K1: g = attributes @ att_g   [500,256], K=1024, split-K 8
    mfma_gemm_bf<<<dim3(8, 2, 8), 256, 0, stream>>>(
        attr_bf, 500, attr_bf, 1000, 500, attgT, attgT,
        gpart_sim, CLS, 256, 1024, 128);

    // K2: reduce 8 partials + row-normalize -> gn bf16
    reduce_norm_kernel<<<CLS, 256, 0, stream>>>(gpart_sim, gn_bf);

    // K3: sim = gn @ gn^T   [500,500], K=256 (overwrites gpart region)
    mfma_gemm_bf<<<dim3(8, 4, 1), 256, 0, stream>>>(
        gn_bf, 500, gn_bf, 1000, 500, gn_bf, gn_bf,
        gpart_sim, CLS, CLS, 256, 256);

    // K4: masked softmax + sparse accumulate -> att_outs bf16
    softmax_att_kernel<<<CLS, 256, 0, stream>>>(gpart_sim, attributes, atto_bf);

    // K5: hid[756,1024] partials: rows 0..255 img@img_w^T, 256..755 att_outs@sem_w^T
    mfma_gemm_bf<<<dim3(12, 8, ks), 256, 0, stream>>>(
        imgf_bf, 256, atto_bf, 4, 500, imgwT, semwT,
        hidP, 756, 1024, 1024, 1024 / ks);

    // K6: fused relu-reduction (sums ks partials + sem_b inline)
    fused_out_partial<<<dim3(BATCH / 64, (CLS + 63) / 64, nh), 256, 0, stream>>>(
        hidP, ks, sem_b, fc_w, outP, HIDDEN_ / nh);

    // K7: finalize
    finalize_kernel<<<(BATCH * CLS + 255) / 256, 256, 0, stream>>>(outP, fc_b, out, nh);
}

// Round 6
// 66.074 us; speedup vs baseline: 4.5853x; 1.0308x over previous
//
#include <hip/hip_runtime.h>
#include <math.h>

#define BATCH 256
#define CLS 500
#define HIDDEN_ 1024
#define T_TEMP_ 10.0f
#define THRESH_ 0.86602540378443864676f
#define NEGV -9.0e15f

typedef __attribute__((ext_vector_type(8))) short short8;
typedef __attribute__((ext_vector_type(8))) unsigned short u16x8;
typedef __attribute__((ext_vector_type(4))) unsigned short u16x4;
typedef __attribute__((ext_vector_type(4))) float f32x4;
typedef __attribute__((ext_vector_type(2))) float f32x2;

static __device__ __forceinline__ unsigned short f2bf(float x) {
    // round-to-nearest-even f32 -> bf16
    unsigned int u = __builtin_bit_cast(unsigned int, x);
    u += 0x7fff + ((u >> 16) & 1);
    return (unsigned short)(u >> 16);
}
static __device__ __forceinline__ float bf2f(unsigned short v) {
    return __builtin_bit_cast(float, (unsigned int)v << 16);
}
static __device__ __forceinline__ u16x8 pack8(const float4& a, const float4& b) {
    u16x8 o;
    o[0] = f2bf(a.x); o[1] = f2bf(a.y); o[2] = f2bf(a.z); o[3] = f2bf(a.w);
    o[4] = f2bf(b.x); o[5] = f2bf(b.y); o[6] = f2bf(b.z); o[7] = f2bf(b.w);
    return o;
}

// ---------------- one-time convert / transpose to bf16 ----------------
// blocks [0,250): attributes cast; [250,378): image_feats cast;
// [378,442): att_g^T; [442,698): img_w^T; [698,954): sem_w^T.
__global__ __launch_bounds__(256) void convert_kernel(
    const float* __restrict__ attrs, const float* __restrict__ imgf,
    const float* __restrict__ attg, const float* __restrict__ imgw,
    const float* __restrict__ semw,
    unsigned short* __restrict__ attrs_bf, unsigned short* __restrict__ imgf_bf,
    unsigned short* __restrict__ attgT, unsigned short* __restrict__ imgwT,
    unsigned short* __restrict__ semwT)
{
    __shared__ unsigned short tb[64][72];   // transpose tile, +8 pad
    const int t = threadIdx.x;
    int bid = blockIdx.x;

    if (bid < 378) {  // plain casts
        const float* s; unsigned short* d; int idx;
        if (bid < 250) { s = attrs; d = attrs_bf; idx = bid * 2048 + t * 8; }
        else           { s = imgf;  d = imgf_bf;  idx = (bid - 250) * 2048 + t * 8; }
        float4 v0 = *(const float4*)&s[idx];
        float4 v1 = *(const float4*)&s[idx + 4];
        *(u16x8*)&d[idx] = pack8(v0, v1);
        return;
    }
    bid -= 378;
    const float* s; unsigned short* d; int Csz;
    if (bid < 64)       { s = attg; d = attgT; Csz = 256; }
    else if (bid < 320) { bid -= 64;  s = imgw; d = imgwT; Csz = 1024; }
    else                { bid -= 320; s = semw; d = semwT; Csz = 1024; }
    const int tiles_c = Csz >> 6;
    const int tr = bid / tiles_c, tc = bid % tiles_c;
    {   // load 64x64 f32 tile coalesced, convert
        const int r = t >> 2, cq = (t & 3) * 16;
        const float* p = &s[(size_t)(tr * 64 + r) * Csz + tc * 64 + cq];
        float4 v0 = *(const float4*)(p);
        float4 v1 = *(const float4*)(p + 4);
        float4 v2 = *(const float4*)(p + 8);
        float4 v3 = *(const float4*)(p + 12);
        *(u16x8*)&tb[r][cq]     = pack8(v0, v1);
        *(u16x8*)&tb[r][cq + 8] = pack8(v2, v3);
    }
    __syncthreads();
    {   // store transposed, coalesced bf16
        const int c = t >> 2, r0 = (t & 3) * 16;
        u16x8 o0, o1;
        #pragma unroll
        for (int i = 0; i < 8; ++i) { o0[i] = tb[r0 + i][c]; o1[i] = tb[r0 + 8 + i][c]; }
        unsigned short* q = &d[(size_t)(tc * 64 + c) * 1024 + tr * 64 + r0];
        *(u16x8*)q = o0;
        *(u16x8*)(q + 8) = o1;
    }
}

// ---------------- unified bf16 MFMA GEMM: C[M,N] = A[M,K] @ B[N,K]^T ----------------
// A row-major bf16 [M][K]; B given as [N][K] bf16 (pre-transposed weights).
// Block tile 64x128, BK=32, 256 threads = 4 waves (2x2 of 32x64 wave tiles).
// Row-region split for fused dispatches (A1 rows then A2 rows, B switches with region).
// gridDim.z = split-K; partials at (C|Cbf) + z*M*N. Cbf non-null -> bf16 output.
__global__ __launch_bounds__(256) void mfma_gemm_bf(
    const unsigned short* __restrict__ A1, int alim1,
    const unsigned short* __restrict__ A2, int a2t0, int alim2,
    const unsigned short* __restrict__ B1, const unsigned short* __restrict__ B2,
    float* __restrict__ C, unsigned short* __restrict__ Cbf,
    int M, int N, int K, int klen)
{
    __shared__ unsigned short As[64][40];    // [row][k], +8 pad
    __shared__ unsigned short Bs[128][40];   // [n][k]

    const int t  = threadIdx.x;
    const int bx = blockIdx.x;
    const int n0 = blockIdx.y * 128;
    const int k0 = blockIdx.z * klen;

    const unsigned short* A; const unsigned short* B; int ar0, alim;
    if (bx < a2t0) { A = A1; B = B1; ar0 = bx * 64;          alim = alim1; }
    else           { A = A2; B = B2; ar0 = (bx - a2t0) * 64; alim = alim2; }

    const int w = t >> 6, lane = t & 63;
    const int wr = w >> 1, wc = w & 1;
    const int fr = lane & 15, kg = lane >> 4;

    const int a_row = t >> 2, a_k = (t & 3) * 8;    // 64 rows x 4 k-octets
    const int b_row = t >> 1, b_k = (t & 1) * 16;   // 128 rows x 2 k-16s
    const int gra = ar0 + a_row;
    const int grb = n0 + b_row;
    const bool va = gra < alim;
    const bool vb = grb < N;
    const size_t abase = (size_t)gra * K + a_k;
    const size_t bbase = (size_t)grb * K + b_k;

    u16x8 zz = {0,0,0,0,0,0,0,0};
    u16x8 pa = zz, pb0 = zz, pb1 = zz;
    if (va) pa = *(const u16x8*)&A[abase + k0];
    if (vb) { pb0 = *(const u16x8*)&B[bbase + k0]; pb1 = *(const u16x8*)&B[bbase + k0 + 8]; }

    f32x4 zero4 = {0.f, 0.f, 0.f, 0.f};
    f32x4 acc[2][4];
    #pragma unroll
    for (int i = 0; i < 2; ++i)
        #pragma unroll
        for (int j = 0; j < 4; ++j) acc[i][j] = zero4;

    for (int kb = k0; kb < k0 + klen; kb += 32) {
        *(u16x8*)&As[a_row][a_k] = pa;
        *(u16x8*)&Bs[b_row][b_k] = pb0;
        *(u16x8*)&Bs[b_row][b_k + 8] = pb1;
        __syncthreads();

        const int kn = kb + 32;           // register prefetch of next tile
        if (kn < k0 + klen) {
            if (va) pa = *(const u16x8*)&A[abase + kn];
            if (vb) { pb0 = *(const u16x8*)&B[bbase + kn]; pb1 = *(const u16x8*)&B[bbase + kn + 8]; }
        }

        short8 af[2], bfr[4];
        #pragma unroll
        for (int i = 0; i < 2; ++i)
            af[i] = *(short8*)&As[wr * 32 + i * 16 + fr][kg * 8];
        #pragma unroll
        for (int j = 0; j < 4; ++j)
            bfr[j] = *(short8*)&Bs[wc * 64 + j * 16 + fr][kg * 8];
        #pragma unroll
        for (int i = 0; i < 2; ++i)
            #pragma unroll
            for (int j = 0; j < 4; ++j)
                acc[i][j] = __builtin_amdgcn_mfma_f32_16x16x32_bf16(
                    af[i], bfr[j], acc[i][j], 0, 0, 0);
        __syncthreads();
    }

    // epilogue: D col = lane&15, row = (lane>>4)*4 + reg
    const int orow0 = bx * 64 + wr * 32, ocol0 = n0 + wc * 64;
    if (Cbf) {
        unsigned short* Cw = Cbf + (size_t)blockIdx.z * M * N;
        #pragma unroll
        for (int i = 0; i < 2; ++i) {
            const int r0 = orow0 + i * 16 + kg * 4;
            #pragma unroll
            for (int j = 0; j < 4; ++j) {
                const int cc = ocol0 + j * 16 + fr;
                if (cc >= N) continue;
                #pragma unroll
                for (int r = 0; r < 4; ++r) {
                    const int rr = r0 + r;
                    if (rr < M) Cw[(size_t)rr * N + cc] = f2bf(acc[i][j][r]);
                }
            }
        }
    } else {
        float* Cw = C + (gridDim.z > 1 ? (size_t)blockIdx.z * M * N : 0);
        #pragma unroll
        for (int i = 0; i < 2; ++i) {
            const int r0 = orow0 + i * 16 + kg * 4;
            #pragma unroll
            for (int j = 0; j < 4; ++j) {
                const int cc = ocol0 + j * 16 + fr;
                if (cc >= N) continue;
                #pragma unroll
                for (int r = 0; r < 4; ++r) {
                    const int rr = r0 + r;
                    if (rr < M) Cw[(size_t)rr * N + cc] = acc[i][j][r];
                }
            }
        }
    }
}

// ---------------- reduce 8 split-K partials + row-normalize -> gn bf16 ----------------
__global__ __launch_bounds__(256) void reduce_norm_kernel(
    const float* __restrict__ part, unsigned short* __restrict__ gn_bf)
{
    const int c = blockIdx.x, t = threadIdx.x;
    float v = 0.f;
    #pragma unroll
    for (int z = 0; z < 8; ++z) v += part[(size_t)z * (CLS * 256) + c * 256 + t];
    float ss = v * v;
    #pragma unroll
    for (int off = 32; off >= 1; off >>= 1) ss += __shfl_down(ss, off);
    __shared__ float red[4];
    const int wave = t >> 6, lane = t & 63;
    if (lane == 0) red[wave] = ss;
    __syncthreads();
    const float tot = red[0] + red[1] + red[2] + red[3];
    const float rn  = 1.f / sqrtf(tot);
    gn_bf[c * 256 + t] = f2bf(v * rn);
}

// ---------------- masked softmax + sparse attention @ attributes (bf16 out) ----------------
__global__ __launch_bounds__(256) void softmax_att_kernel(
    const float* __restrict__ sim, const float* __restrict__ attrs,
    unsigned short* __restrict__ att_outs)
{
    const int c = blockIdx.x, t = threadIdx.x;
    __shared__ float p_s[512];
    __shared__ float redm[4];
    __shared__ float reds[4];

    const float d0 = sim[(size_t)c * CLS + t];
    const float d1 = (t + 256 < CLS) ? sim[(size_t)c * CLS + t + 256] : NEGV;

    float vmax = fmaxf((d0 > THRESH_) ? d0 : NEGV, (d1 > THRESH_) ? d1 : NEGV);
    #pragma unroll
    for (int off = 32; off >= 1; off >>= 1) vmax = fmaxf(vmax, __shfl_down(vmax, off));
    const int wave = t >> 6, lane = t & 63;
    if (lane == 0) redm[wave] = vmax;
    __syncthreads();
    const float m = fmaxf(fmaxf(redm[0], redm[1]), fmaxf(redm[2], redm[3]));

    const float p0 = (d0 > THRESH_) ? expf(T_TEMP_ * (d0 - m)) : 0.f;
    const float p1 = (d1 > THRESH_) ? expf(T_TEMP_ * (d1 - m)) : 0.f;
    p_s[t] = p0;
    p_s[t + 256] = p1;
    float vsum = p0 + p1;
    #pragma unroll
    for (int off = 32; off >= 1; off >>= 1) vsum += __shfl_down(vsum, off);
    if (lane == 0) reds[wave] = vsum;
    __syncthreads();   // orders p_s before the scan
    const float inv = 1.f / (reds[0] + reds[1] + reds[2] + reds[3]);

    // ballot-compacted sparse accumulate (rows are exactly sparse)
    float acc[4] = {0.f, 0.f, 0.f, 0.f};
    for (int base = 0; base < 512; base += 64) {
        const float pv_l = p_s[base + lane];
        unsigned long long mask = __ballot(pv_l > 0.f);
        while (mask) {
            const int l = __ffsll((long long)mask) - 1;
            mask &= mask - 1;
            const int c2 = base + l;
            const float pv = p_s[c2];
            const float* ar = &attrs[(size_t)c2 * 1024 + t];
            #pragma unroll
            for (int j = 0; j < 4; ++j) acc[j] += pv * ar[256 * j];
        }
    }
    #pragma unroll
    for (int j = 0; j < 4; ++j)
        att_outs[(size_t)c * 1024 + t + 256 * j] = f2bf(acc[j] * inv);
}

// ---------------- fused relu-reduction (bf16 partials in, packed f32 math) ----------------
// part: bf16 [ks][756][1024] (rows 0..255 img_h partials, 256..755 sem_h partials)
// outpart[nh][b][c] = sum_{h in chunk} relu(img_h[b,h]+sem_h[c,h]+sem_b[h]) * fc_w[h]
__global__ __launch_bounds__(256) void fused_out_partial(
    const unsigned short* __restrict__ part, int ks, const float* __restrict__ sem_b,
    const float* __restrict__ fc_w, float* __restrict__ outpart, int h_per)
{
    __shared__ float imgs[64][68];
    __shared__ float sems[64][68];
    __shared__ float fcs[128];

    const size_t pstride = (size_t)756 * 1024;
    const int t  = threadIdx.x;
    const int tb = t >> 4, tc = t & 15;
    const int b0 = blockIdx.x * 64, c0 = blockIdx.y * 64;
    const int h0 = blockIdx.z * h_per;

    if (t < (h_per >> 2)) *(float4*)&fcs[t * 4] = *(const float4*)&fc_w[h0 + t * 4];

    f32x2 acc2[4][4];
    #pragma unroll
    for (int i = 0; i < 4; ++i)
        #pragma unroll
        for (int j = 0; j < 4; ++j) acc2[i][j] = (f32x2){0.f, 0.f};

    for (int hs = 0; hs < (h_per >> 6); ++hs) {
        const int hb = h0 + hs * 64;
        #pragma unroll
        for (int i = 0; i < 4; ++i) {
            const int row = (t >> 4) + 16 * i;
            const int col = (t & 15) * 4;
            // img rows: sum ks bf16 partials
            f32x4 iv = {0.f, 0.f, 0.f, 0.f};
            const unsigned short* pi = &part[(size_t)(b0 + row) * 1024 + hb + col];
            for (int z = 0; z < ks; ++z) {
                u16x4 vz = *(const u16x4*)(pi + (size_t)z * pstride);
                iv[0] += bf2f(vz[0]); iv[1] += bf2f(vz[1]);
                iv[2] += bf2f(vz[2]); iv[3] += bf2f(vz[3]);
            }
            *(f32x4*)&imgs[row][col] = iv;

            f32x4 sv = {0.f, 0.f, 0.f, 0.f};
            if (c0 + row < CLS) {
                const unsigned short* ps = &part[(size_t)(256 + c0 + row) * 1024 + hb + col];
                for (int z = 0; z < ks; ++z) {
                    u16x4 vz = *(const u16x4*)(ps + (size_t)z * pstride);
                    sv[0] += bf2f(vz[0]); sv[1] += bf2f(vz[1]);
                    sv[2] += bf2f(vz[2]); sv[3] += bf2f(vz[3]);
                }
                float4 bb = *(const float4*)&sem_b[hb + col];
                sv[0] += bb.x; sv[1] += bb.y; sv[2] += bb.z; sv[3] += bb.w;
            }
            *(f32x4*)&sems[row][col] = sv;
        }
        __syncthreads();

        #pragma unroll
        for (int h4 = 0; h4 < 16; ++h4) {
            float4 ia[4], sa[4];
            #pragma unroll
            for (int i = 0; i < 4; ++i) ia[i] = *(float4*)&imgs[tb + 16 * i][h4 * 4];
            #pragma unroll
            for (int j = 0; j < 4; ++j) sa[j] = *(float4*)&sems[tc + 16 * j][h4 * 4];
            const float4 wv = *(const float4*)&fcs[hs * 64 + h4 * 4];
            #pragma unroll
            for (int e2 = 0; e2 < 2; ++e2) {
                const f32x2 w2 = {(&wv.x)[2 * e2], (&wv.x)[2 * e2 + 1]};
                f32x2 ia2[4], sa2[4];
                #pragma unroll
                for (int i = 0; i < 4; ++i)
                    ia2[i] = (f32x2){(&ia[i].x)[2 * e2], (&ia[i].x)[2 * e2 + 1]};
                #pragma unroll
                for (int j = 0; j < 4; ++j)
                    sa2[j] = (f32x2){(&sa[j].x)[2 * e2], (&sa[j].x)[2 * e2 + 1]};
                #pragma unroll
                for (int i = 0; i < 4; ++i)
                    #pragma unroll
                    for (int j = 0; j < 4; ++j) {
                        f32x2 s = ia2[i] + sa2[j];
                        s = __builtin_elementwise_max(s, (f32x2){0.f, 0.f});
                        acc2[i][j] += s * w2;   // v_pk_fma_f32 candidates
                    }
            }
        }
        __syncthreads();
    }

    const int nh = blockIdx.z;
    #pragma unroll
    for (int i = 0; i < 4; ++i) {
        const int b = b0 + tb + 16 * i;
        #pragma unroll
        for (int j = 0; j < 4; ++j) {
            const int cc = c0 + tc + 16 * j;
            if (cc < CLS)
                outpart[((size_t)nh * BATCH + b) * CLS + cc] = acc2[i][j][0] + acc2[i][j][1];
        }
    }
}

// ---------------- finalize ----------------
__global__ __launch_bounds__(256) void finalize_kernel(
    const float* __restrict__ partial, const float* __restrict__ fc_b,
    float* __restrict__ out, int nsplit)
{
    const int idx = blockIdx.x * 256 + threadIdx.x;
    if (idx >= BATCH * CLS) return;
    float s = fc_b[0];
    for (int nh = 0; nh < nsplit; ++nh)
        s += partial[(size_t)nh * BATCH * CLS + idx];
    out[idx] = s;
}

extern "C" void kernel_launch(void* const* d_in, const int* in_sizes, int n_in,
                              void* d_out, int out_size, void* d_ws, size_t ws_size,
                              hipStream_t stream)
{
    const float* image_feats = (const float*)d_in[0];
    const float* attributes  = (const float*)d_in[1];
    const float* att_g       = (const float*)d_in[3];
    const float* img_w       = (const float*)d_in[4];
    const float* sem_w       = (const float*)d_in[5];
    const float* sem_b       = (const float*)d_in[6];
    const float* fc_w        = (const float*)d_in[7];
    const float* fc_b        = (const float*)d_in[8];
    float* out = (float*)d_out;

    char* ws = (char*)d_ws;
    size_t off = 0;
    auto alloc = [&](size_t b) { size_t o = off; off = (off + b + 255) & ~(size_t)255; return o; };
    const size_t o_attr = alloc((size_t)500 * 1024 * 2);   // attributes bf16
    const size_t o_imgf = alloc((size_t)256 * 1024 * 2);   // image_feats bf16
    const size_t o_attg = alloc((size_t)256 * 1024 * 2);   // att_g^T bf16  [256][1024]
    const size_t o_imgw = alloc((size_t)1024 * 1024 * 2);  // img_w^T bf16  [1024][1024]
    const size_t o_semw = alloc((size_t)1024 * 1024 * 2);  // sem_w^T bf16
    const size_t o_gn   = alloc((size_t)500 * 256 * 2);    // gn bf16
    const size_t o_atto = alloc((size_t)500 * 1024 * 2);   // att_outs bf16
    const size_t o_gp   = alloc((size_t)8 * 500 * 256 * 4);// g partials / sim (time-disjoint)
    const size_t base   = off;

    int ks = 4, nh = 16;   // ws_size ~256 MiB; guard anyway
    while (base + (size_t)ks * 756 * 1024 * 2 + (size_t)nh * BATCH * CLS * 4 + 512 > ws_size) {
        if (ks > 1) ks >>= 1;
        else if (nh > 8) nh = 8;
        else break;
    }
    const size_t o_hidp = alloc((size_t)ks * 756 * 1024 * 2);   // bf16 partials
    const size_t o_outp = alloc((size_t)nh * BATCH * CLS * 4);
    (void)o_outp;

    unsigned short* attr_bf = (unsigned short*)(ws + o_attr);
    unsigned short* imgf_bf = (unsigned short*)(ws + o_imgf);
    unsigned short* attgT   = (unsigned short*)(ws + o_attg);
    unsigned short* imgwT   = (unsigned short*)(ws + o_imgw);
    unsigned short* semwT   = (unsigned short*)(ws + o_semw);
    unsigned short* gn_bf   = (unsigned short*)(ws + o_gn);
    unsigned short* atto_bf = (unsigned short*)(ws + o_atto);
    float* gpart_sim        = (float*)(ws + o_gp);
    unsigned short* hidP    = (unsigned short*)(ws + o_hidp);
    float* outP             = (float*)(ws + o_outp);

    // K0: convert + transpose everything to bf16 once
    convert_kernel<<<954, 256, 0, stream>>>(
        attributes, image_feats, att_g, img_w, sem_w,
        attr_bf, imgf_bf, attgT, imgwT, semwT);

    // K1: g = attributes @ att_g   [500,256], K=1024, split-K 8 (f32 partials)
    mfma_gemm_bf<<<dim3(8, 2, 8), 256, 0, stream>>>(
        attr_bf, 500, attr_bf, 1000, 500, attgT, attgT,
        gpart_sim, nullptr, CLS, 256, 1024, 128);

    // K2: reduce 8 partials + row-normalize -> gn bf16
    reduce_norm_kernel<<<CLS, 256, 0, stream>>>(gpart_sim, gn_bf);

    // K3: sim = gn @ gn^T   [500,500], K=256 (f32, overwrites gpart region)
    mfma_gemm_bf<<<dim3(8, 4, 1), 256, 0, stream>>>(
        gn_bf, 500, gn_bf, 1000, 500, gn_bf, gn_bf,
        gpart_sim, nullptr, CLS, CLS, 256, 256);

    // K4: masked softmax + sparse accumulate -> att_outs bf16
    softmax_att_kernel<<<CLS, 256, 0, stream>>>(gpart_sim, attributes, atto_bf);

    // K5: hid[756,1024] bf16 partials: rows 0..255 img@img_w^T, 256..755 att_outs@sem_w^T
    mfma_gemm_bf<<<dim3(12, 8, ks), 256, 0, stream>>>(
        imgf_bf, 256, atto_bf, 4, 500, imgwT, semwT,
        nullptr, hidP, 756, 1024, 1024, 1024 / ks);

    // K6: fused relu-reduction (sums ks bf16 partials + sem_b inline, packed f32 math)
    fused_out_partial<<<dim3(BATCH / 64, (CLS + 63) / 64, nh), 256, 0, stream>>>(
        hidP, ks, sem_b, fc_w, outP, HIDDEN_ / nh);

    // K7: finalize
    finalize_kernel<<<(BATCH * CLS + 255) / 256, 256, 0, stream>>>(outP, fc_b, out, nh);
}